// Round 5
// baseline (375.056 us; speedup 1.0000x reference)
//
#include <hip/hip_runtime.h>
#include <hip/hip_bf16.h>

#define BD 8
#define CD 128
#define HD 96
#define WD 96
#define HW (HD*WD)          // 9216
#define NPIX (BD*HW)        // 73728
#define NTOT ((size_t)BD*CD*HW) // 9437184
#define WC 144
#define NG 16
#define KWRE_OFF 37617664   // scratch inside d_out (y overwrites it later)
// xb16 (bf16 x) lives at d_out[0 .. 18.9MB) during the front half; y overwrites later.

typedef __hip_bfloat16 bf16;
typedef __attribute__((ext_vector_type(8))) short s8v;   // 8 bf16 (A/B frag)
typedef __attribute__((ext_vector_type(4))) float f4v;   // 4 f32 (C/D frag)
typedef __attribute__((ext_vector_type(4))) short s4vv;  // 4 bf16 (8B LDS read)

__device__ __forceinline__ float b2f(bf16 v){ return __bfloat162float(v); }
__device__ __forceinline__ bf16  f2b(float v){ return __float2bfloat16(v); }
__device__ __forceinline__ short f2bs(float f){ union{ bf16 h; short s; } u; u.h = f2b(f); return u.s; }
__device__ __forceinline__ float bs2f(short s){ union{ bf16 h; short s; } u; u.s = s; return b2f(u.h); }

struct TensPtrs { const void* p[14]; };

__device__ __constant__ int dNelem[14] = {
    9437184, 36864, 16384, 9216, 144, 144, 144, 16384, 128, 128, 8192, 64, 16384, 256
};
__device__ __constant__ int dCanonOff[14] = {
    0, 0, 36864, 53248, 62464, 62608, 62752, 62896, 79280, 79408, 79536, 87728, 87792, 104176
};
__device__ __constant__ int dBOff[14] = {
    -1, 0, 36864, 53248, -1, -1, -1, 62464, -1, -1, -1, -1, -1, -1
};
#define CO_EB2  62464
#define CO_GNG  62608
#define CO_GNB  62752
#define CO_BNG  79280
#define CO_BNB  79408
#define CO_SW1  79536
#define CO_SB1  87728
#define CO_SW2  87792
#define CO_SB2  104176
#define BO_KW   0
#define BO_EW1  36864
#define BO_EW2  53248
#define BO_C1W  62464

// swizzled LDS address helpers: byte ^= ((px>>3)&7)<<4  (breaks 8-px-stride bank aliasing)
__device__ __forceinline__ char* qk_sw(short* base, int px, int e){
    return (char*)base + ((((px*136 + e)*2)) ^ (((px>>3)&7)<<4));
}
__device__ __forceinline__ char* xt_sw(short* base, int px, int e){
    return (char*)base + (((px*32 + e)*2) ^ (((px>>3)&7)<<4));
}
// pack a ch-pair column into pixel-major LDS
__device__ __forceinline__ void qk_write(short* qk, int p8, int c, s8v t0, s8v t1){
    #pragma unroll
    for (int jj = 0; jj < 8; ++jj){
        int px = p8*8 + jj;
        unsigned int pk = (unsigned int)(unsigned short)t0[jj]
                        | ((unsigned int)(unsigned short)t1[jj] << 16);
        *(unsigned int*)qk_sw(qk, px, c) = pk;
    }
}

// ---------------- detect (256 threads, 4B pair loads) ----------------
__global__ void k_detect(TensPtrs tp, int* __restrict__ flags){
    int i = blockIdx.x; int tid = threadIdx.x;
    int n = dNelem[i];
    int m = n < 4096 ? n : 4096;
    int pairs = m >> 1;
    const unsigned int* u = (const unsigned int*)tp.p[i];
    int v = 0;
    for (int j = tid; j < pairs; j += 256){
        unsigned int w = u[j];
        unsigned short lo = (unsigned short)(w & 0xffff);
        unsigned short hi = (unsigned short)(w >> 16);
        int e = (lo >> 7) & 0xFF;
        bool wild = (e >= 0xBE) || (e > 0 && e < 0x40);
        if (wild || (lo == 0 && hi != 0)) v++;
    }
    __shared__ int sv[256];
    sv[tid] = v; __syncthreads();
    for (int st = 128; st > 0; st >>= 1){
        if (tid < st) sv[tid] += sv[tid+st];
        __syncthreads();
    }
    if (tid == 0) flags[i] = (sv[0]*8 > pairs) ? 1 : 0;
}

// ---------------- canon (16 chunk-blocks per tensor) ----------------
__global__ void k_canon(TensPtrs tp, const int* __restrict__ flags,
                        float* __restrict__ canonf, short* __restrict__ canonb){
    int i = (blockIdx.x >> 4) + 1;            // 13 tensors x 16 chunks
    int chunk = blockIdx.x & 15;
    int n = dNelem[i]; int off = dCanonOff[i]; int bo = dBOff[i];
    bool f32 = flags[i] != 0;
    for (int j = chunk*256 + threadIdx.x; j < n; j += 4096){
        float v = f32 ? ((const float*)tp.p[i])[j] : b2f(((const bf16*)tp.p[i])[j]);
        canonf[off + j] = v;
        if (bo >= 0) canonb[bo + j] = f2bs(v);
    }
}

// ---------------- xcast: only needed for f32 x; bf16 x is consumed in place ----------------
__global__ void k_xcast(const void* __restrict__ x, const int* __restrict__ flags,
                        unsigned short* __restrict__ xb){
    if (!flags[0]) return;                    // bf16 input: consumers read x directly
    int blk = blockIdx.x;                     // 1024 = 8b x 128; 2304 vec4 each
    size_t base = ((size_t)((blk & 7)*128 + (blk >> 3)))*2304;
    for (int k = 0; k < 9; ++k){
        size_t i = base + k*256 + threadIdx.x;
        float4 v = ((const float4*)x)[i];
        ushort4 o;
        o.x = (unsigned short)f2bs(v.x); o.y = (unsigned short)f2bs(v.y);
        o.z = (unsigned short)f2bs(v.z); o.w = (unsigned short)f2bs(v.w);
        ((ushort4*)xb)[i] = o;
    }
}

// ---------------- reorder key weights: [g][oc][ic][t] -> [g][t][oc][ic] ----------------
__global__ void k_reorder_kw(const short* __restrict__ canonb, short* __restrict__ kwre){
    int idx = blockIdx.x*256 + threadIdx.x;   // 36864
    if (idx >= 36864) return;
    int g = idx / 9216, rem = idx - g*9216;
    int oc = rem / 288, r2 = rem - oc*288;
    int ic = r2 / 9, t = r2 - ic*9;
    kwre[g*9216 + t*1024 + oc*32 + ic] = canonb[BO_KW + idx];
}

__global__ void k_zero(float* __restrict__ p, int n){
    int i = blockIdx.x*256 + threadIdx.x;
    if (i < n) p[i] = 0.f;
}

// ---------------- keyconv MFMA (+fused Sum(relu k) for SE gap; b-locked XCD swizzle) ----------------
__global__ void k_keyconv_mfma(const short* __restrict__ xb, const short* __restrict__ xorig,
                               const int* __restrict__ flags,
                               const short* __restrict__ kwre, bf16* __restrict__ kout,
                               float* __restrict__ kgap){
    __shared__ short xt[588*32];     // [pixel(6x98)][ic], XOR-swizzled bytes, 37632 B
    int blk = blockIdx.x;            // 768 = 8b x 96(j)
    int b = blk & 7, j = blk >> 3;
    int band = j % 24, g = j / 24;
    int r0 = band*4;
    int tid = threadIdx.x;
    const short* xs = flags[0] ? xb : xorig;
    // interior pixels (icol 0..95) : 6 rows x 16 ch-pairs x 12 groups of 8 px
    for (int idx = tid; idx < 1152; idx += 256){
        int pr = idx / 192, rem = idx - pr*192;
        int c2 = rem / 12, gx = rem - c2*12;
        int ir = r0 - 1 + pr;
        int c = c2*2;
        s8v t0 = (s8v){0,0,0,0,0,0,0,0};
        s8v t1 = (s8v){0,0,0,0,0,0,0,0};
        if ((unsigned)ir < 96u){
            size_t gb = ((size_t)b*CD + g*32 + c)*HW + (size_t)ir*WD + gx*8;
            t0 = *(const s8v*)(xs + gb);
            t1 = *(const s8v*)(xs + gb + HW);
        }
        #pragma unroll
        for (int jj = 0; jj < 8; ++jj){
            int pxl = pr*98 + gx*8 + 1 + jj;
            unsigned int pk = (unsigned int)(unsigned short)t0[jj]
                            | ((unsigned int)(unsigned short)t1[jj] << 16);
            *(unsigned int*)xt_sw(xt, pxl, c) = pk;
        }
    }
    // edge columns pc=0 (icol=-1) and pc=97 (icol=96): zero
    for (int idx = tid; idx < 192; idx += 256){
        int pr = idx / 32, rem = idx - pr*32;
        int e = rem >> 4, c2 = rem & 15;
        int pxl = pr*98 + (e ? 97 : 0);
        *(unsigned int*)xt_sw(xt, pxl, c2*2) = 0u;
    }
    __syncthreads();
    int wave = tid >> 6, lane = tid & 63, l15 = lane & 15, quad = lane >> 4;
    f4v acc[2][6];
    #pragma unroll
    for (int m = 0; m < 2; ++m)
        #pragma unroll
        for (int n = 0; n < 6; ++n) acc[m][n] = (f4v){0.f,0.f,0.f,0.f};
    const short* kg = kwre + g*9216;
    for (int t = 0; t < 9; ++t){
        s8v A0 = *(const s8v*)(kg + t*1024 + l15*32 + quad*8);
        s8v A1 = *(const s8v*)(kg + t*1024 + (16+l15)*32 + quad*8);
        int pbase = (wave + t/3)*98 + (t%3) + l15;
        #pragma unroll
        for (int n = 0; n < 6; ++n){
            int pxl = pbase + n*16;
            s8v B = *(const s8v*)xt_sw(xt, pxl, quad*8);
            acc[0][n] = __builtin_amdgcn_mfma_f32_16x16x32_bf16(A0, B, acc[0][n], 0, 0, 0);
            acc[1][n] = __builtin_amdgcn_mfma_f32_16x16x32_bf16(A1, B, acc[1][n], 0, 0, 0);
        }
    }
    int r = r0 + wave;
    #pragma unroll
    for (int m = 0; m < 2; ++m)
        #pragma unroll
        for (int n = 0; n < 6; ++n)
            #pragma unroll
            for (int reg = 0; reg < 4; ++reg){
                int oc = g*32 + m*16 + quad*4 + reg;
                int px = n*16 + l15;
                kout[((size_t)b*CD + oc)*HW + r*WD + px] = f2b(fmaxf(acc[m][n][reg], 0.f));
            }
    // fused Sum(relu k) over this block's 4 rows x 96 px per oc -> SE gap accumulator
    #pragma unroll
    for (int m = 0; m < 2; ++m)
        #pragma unroll
        for (int reg = 0; reg < 4; ++reg){
            float s = 0.f;
            #pragma unroll
            for (int n = 0; n < 6; ++n) s += fmaxf(acc[m][n][reg], 0.f);
            #pragma unroll
            for (int off = 1; off < 16; off <<= 1) s += __shfl_xor(s, off);
            if (l15 == 0){
                int oc = g*32 + m*16 + quad*4 + reg;
                atomicAdd(&kgap[b*CD + oc], s);
            }
        }
}

// ---------------- vconv MFMA (fallback path only) ----------------
__global__ void k_vconv_mfma(const void* __restrict__ x, const int* __restrict__ flags,
                             const short* __restrict__ c1wb, bf16* __restrict__ vout){
    __shared__ short xt[96*136];
    int blk = blockIdx.x; int b = blk / 96, r = blk % 96;
    int tid = threadIdx.x;
    bool F = flags[0] != 0;
    for (int idx = tid; idx < 1536; idx += 256){
        int oct = idx / 96, px = idx - oct*96;
        size_t base = ((size_t)b*CD + oct*8)*HW + r*WD + px;
        s8v tmp;
        #pragma unroll
        for (int j = 0; j < 8; ++j){
            float v = F ? ((const float*)x)[base + (size_t)j*HW]
                        : b2f(((const bf16*)x)[base + (size_t)j*HW]);
            tmp[j] = f2bs(v);
        }
        *(s8v*)(xt + px*136 + oct*8) = tmp;
    }
    __syncthreads();
    int wave = tid >> 6, lane = tid & 63, l15 = lane & 15, quad = lane >> 4;
    f4v acc[2][6];
    #pragma unroll
    for (int m = 0; m < 2; ++m)
        #pragma unroll
        for (int n = 0; n < 6; ++n) acc[m][n] = (f4v){0.f,0.f,0.f,0.f};
    for (int k0 = 0; k0 < 128; k0 += 32){
        s8v Bf[6];
        #pragma unroll
        for (int n = 0; n < 6; ++n) Bf[n] = *(const s8v*)(xt + (n*16+l15)*136 + k0 + quad*8);
        #pragma unroll
        for (int m = 0; m < 2; ++m){
            int oc0 = (wave*2 + m)*16;
            s8v A = *(const s8v*)(c1wb + BO_C1W + (oc0 + l15)*128 + k0 + quad*8);
            #pragma unroll
            for (int n = 0; n < 6; ++n)
                acc[m][n] = __builtin_amdgcn_mfma_f32_16x16x32_bf16(A, Bf[n], acc[m][n], 0, 0, 0);
        }
    }
    #pragma unroll
    for (int m = 0; m < 2; ++m)
        #pragma unroll
        for (int n = 0; n < 6; ++n)
            #pragma unroll
            for (int reg = 0; reg < 4; ++reg){
                int oc = (wave*2+m)*16 + quad*4 + reg;
                int px = n*16 + l15;
                vout[((size_t)b*CD + oc)*HW + r*WD + px] = f2b(acc[m][n][reg]);
            }
}

// ================= FAST PATH =================
// embed STATS + fused vconv; k-half register-prefetch (T14); b-locked XCD swizzle
__global__ void k_embed_stats(const short* __restrict__ xb, const short* __restrict__ xorig,
                              const int* __restrict__ flags,
                              const bf16* __restrict__ kbuf, const short* __restrict__ canonb,
                              const float* __restrict__ canonf,
                              unsigned short* __restrict__ w1b, bf16* __restrict__ vout,
                              float* __restrict__ gsum_s, float* __restrict__ gsq_s){
    __shared__ short qk[48*136];     // 13056 B, XOR-swizzled, one 128-ch half at a time
    __shared__ short w1s[48*72];     // 6912 B
    __shared__ float gacc[16], gacc2[16];
    const short* ew1b = canonb + BO_EW1;
    const short* ew2b = canonb + BO_EW2;
    const float* eb2f = canonf + CO_EB2;
    int blk = blockIdx.x;            // 1536 = 8b x 192(j)
    int b = blk & 7, j = blk >> 3;
    int px0 = (j & 1)*48, r = j >> 1;
    int tid = threadIdx.x;
    int wave = tid >> 6, lane = tid & 63, l15 = lane & 15, quad = lane >> 4;
    const short* xs = flags[0] ? xb : xorig;
    const short* kb = (const short*)kbuf;
    if (tid < 16){ gacc[tid] = 0.f; gacc2[tid] = 0.f; }
    // ---- per-thread staging coords: item A = tid (all), item B = 256+tid (tid<128) ----
    int c2a = tid / 6, p8a = tid - c2a*6;
    size_t gba = ((size_t)b*CD + c2a*2)*HW + r*WD + px0 + p8a*8;
    bool has2 = tid < 128;
    int ib = 256 + tid;
    int c2b = ib / 6, p8b = ib - c2b*6;
    size_t gbb = ((size_t)b*CD + c2b*2)*HW + r*WD + px0 + p8b*8;
    // issue ALL loads up front: x half + k half (k stays in regs until after vconv)
    s8v xa0 = *(const s8v*)(xs + gba);
    s8v xa1 = *(const s8v*)(xs + gba + HW);
    s8v ka0 = *(const s8v*)(kb + gba);
    s8v ka1 = *(const s8v*)(kb + gba + HW);
    s8v xb0, xb1, kb0, kb1;
    if (has2){
        xb0 = *(const s8v*)(xs + gbb);
        xb1 = *(const s8v*)(xs + gbb + HW);
        kb0 = *(const s8v*)(kb + gbb);
        kb1 = *(const s8v*)(kb + gbb + HW);
    }
    // write x to LDS
    qk_write(qk, p8a, c2a*2, xa0, xa1);
    if (has2) qk_write(qk, p8b, c2b*2, xb0, xb1);
    __syncthreads();
    // ---- GEMM1 half 1 ----
    f4v a1[3];
    #pragma unroll
    for (int n = 0; n < 3; ++n) a1[n] = (f4v){0.f,0.f,0.f,0.f};
    int mb = wave*16;
    for (int k0 = 0; k0 < 128; k0 += 32){
        s8v A = *(const s8v*)(ew1b + (mb + l15)*256 + k0 + quad*8);
        #pragma unroll
        for (int n = 0; n < 3; ++n){
            int px = n*16 + l15;
            s8v Bf = *(const s8v*)qk_sw(qk, px, k0 + quad*8);
            a1[n] = __builtin_amdgcn_mfma_f32_16x16x32_bf16(A, Bf, a1[n], 0, 0, 0);
        }
    }
    // ---- fused vconv GEMM: v[128 x 48] = C1W[128x128] * X[128x48] ----
    {
        f4v av[2][3];
        #pragma unroll
        for (int m = 0; m < 2; ++m)
            #pragma unroll
            for (int n = 0; n < 3; ++n) av[m][n] = (f4v){0.f,0.f,0.f,0.f};
        for (int k0 = 0; k0 < 128; k0 += 32){
            s8v Bf[3];
            #pragma unroll
            for (int n = 0; n < 3; ++n){
                int px = n*16 + l15;
                Bf[n] = *(const s8v*)qk_sw(qk, px, k0 + quad*8);
            }
            #pragma unroll
            for (int m = 0; m < 2; ++m){
                int oc0 = (wave*2 + m)*16;
                s8v A = *(const s8v*)(canonb + BO_C1W + (oc0 + l15)*128 + k0 + quad*8);
                #pragma unroll
                for (int n = 0; n < 3; ++n)
                    av[m][n] = __builtin_amdgcn_mfma_f32_16x16x32_bf16(A, Bf[n], av[m][n], 0, 0, 0);
            }
        }
        #pragma unroll
        for (int m = 0; m < 2; ++m)
            #pragma unroll
            for (int n = 0; n < 3; ++n)
                #pragma unroll
                for (int reg = 0; reg < 4; ++reg){
                    int oc = (wave*2+m)*16 + quad*4 + reg;
                    int px = n*16 + l15;
                    vout[((size_t)b*CD + oc)*HW + r*WD + px0 + px] = f2b(av[m][n][reg]);
                }
    }
    __syncthreads();
    // ---- write prefetched k half to LDS (loads long since landed) ----
    qk_write(qk, p8a, c2a*2, ka0, ka1);
    if (has2) qk_write(qk, p8b, c2b*2, kb0, kb1);
    __syncthreads();
    for (int k0 = 128; k0 < 256; k0 += 32){
        s8v A = *(const s8v*)(ew1b + (mb + l15)*256 + k0 + quad*8);
        #pragma unroll
        for (int n = 0; n < 3; ++n){
            int px = n*16 + l15;
            s8v Bf = *(const s8v*)qk_sw(qk, px, (k0-128) + quad*8);
            a1[n] = __builtin_amdgcn_mfma_f32_16x16x32_bf16(A, Bf, a1[n], 0, 0, 0);
        }
    }
    #pragma unroll
    for (int n = 0; n < 3; ++n)
        #pragma unroll
        for (int reg = 0; reg < 4; ++reg){
            int ch = mb + quad*4 + reg;
            int px = n*16 + l15;
            w1s[px*72 + ch] = f2bs(fmaxf(a1[n][reg], 0.f));
        }
    __syncthreads();
    size_t gpx0 = (size_t)b*HW + r*WD + px0;
    for (int idx = tid; idx < 768; idx += 256){
        int px = idx >> 4, s4 = idx & 15;
        ushort4 v4 = *(const ushort4*)((const unsigned short*)w1s + px*72 + s4*4);
        *(ushort4*)(w1b + (gpx0 + px)*64 + s4*4) = v4;
    }
    // ---- GEMM2 + frag-level GN moment reduction ----
    {
        f4v a2[3][3];
        #pragma unroll
        for (int i = 0; i < 3; ++i)
            #pragma unroll
            for (int n = 0; n < 3; ++n) a2[i][n] = (f4v){0.f,0.f,0.f,0.f};
        for (int k0 = 0; k0 < 64; k0 += 32){
            s8v Bf[3];
            #pragma unroll
            for (int n = 0; n < 3; ++n) Bf[n] = *(const s8v*)(w1s + (n*16+l15)*72 + k0 + quad*8);
            #pragma unroll
            for (int i = 0; i < 3; ++i){
                int mt = wave + i*4;
                if (mt >= 9) break;
                s8v A = *(const s8v*)(ew2b + (mt*16 + l15)*64 + k0 + quad*8);
                #pragma unroll
                for (int n = 0; n < 3; ++n)
                    a2[i][n] = __builtin_amdgcn_mfma_f32_16x16x32_bf16(A, Bf[n], a2[i][n], 0, 0, 0);
            }
        }
        #pragma unroll
        for (int i = 0; i < 3; ++i){
            int mt = wave + i*4;
            if (mt >= 9) break;
            #pragma unroll
            for (int n = 0; n < 3; ++n)
                #pragma unroll
                for (int reg = 0; reg < 4; ++reg){
                    int o = mt*16 + quad*4 + reg;
                    float v = a2[i][n][reg] + eb2f[o];
                    float s = v, q = v*v;
                    #pragma unroll
                    for (int off = 1; off < 16; off <<= 1){
                        s += __shfl_xor(s, off);
                        q += __shfl_xor(q, off);
                    }
                    if (l15 == 0){
                        int g = o / 9;
                        atomicAdd(&gacc[g], s);
                        atomicAdd(&gacc2[g], q);
                    }
                }
        }
    }
    __syncthreads();
    if (tid < 16){
        int slot = j & 63;
        atomicAdd(&gsum_s[(b*NG + tid)*64 + slot], gacc[tid]);
        atomicAdd(&gsq_s [(b*NG + tid)*64 + slot], gacc2[tid]);
    }
}

// ---------------- embed APPLY (+fused BN stats; b-locked XCD swizzle) ----------------
__global__ void k_embed_apply(const unsigned short* __restrict__ w1b,
                              const short* __restrict__ canonb, const float* __restrict__ canonf,
                              const float* __restrict__ gmean, const float* __restrict__ gistd,
                              const bf16* __restrict__ vbuf, float* __restrict__ yout,
                              float* __restrict__ bnsum_s, float* __restrict__ bnss_s){
    __shared__ short w2s[9216];               // 18432 B  [g(16)][px(48)][12] tap-major
    __shared__ short w1s[48*72];              // 6912 B (unioned with bns/bnq after GEMM2)
    __shared__ float wsc[WC], wbi[WC];        // 1152 B
    float* bns = (float*)w1s;                 // [128] after GEMM2
    float* bnq = bns + 128;                   // [128]
    const short* ew2b = canonb + BO_EW2;
    const float* eb2f = canonf + CO_EB2;
    int blk = blockIdx.x;                     // 1536 = 8b x 192(j)
    int b = blk & 7, j = blk >> 3;
    int px0 = (j & 1)*48, r = j >> 1;
    int tid = threadIdx.x;
    int wave = tid >> 6, lane = tid & 63, l15 = lane & 15, quad = lane >> 4;
    if (tid < WC){
        int g = tid/9;
        float m = gmean[b*NG+g], is = gistd[b*NG+g];
        float ga = canonf[CO_GNG + tid], be = canonf[CO_GNB + tid];
        wsc[tid] = is*ga; wbi[tid] = be - m*is*ga;
    }
    size_t gpx0 = (size_t)b*HW + r*WD + px0;
    for (int idx = tid; idx < 768; idx += 256){
        int px = idx >> 4, s4 = idx & 15;
        ushort4 v4 = *(const ushort4*)(w1b + (gpx0 + px)*64 + s4*4);
        *(ushort4*)((unsigned short*)w1s + px*72 + s4*4) = v4;
    }
    __syncthreads();
    // ---- GEMM2 -> GN-applied, edge-masked, tap-major w2s ----
    {
        f4v a2[3][3];
        #pragma unroll
        for (int i = 0; i < 3; ++i)
            #pragma unroll
            for (int n = 0; n < 3; ++n) a2[i][n] = (f4v){0.f,0.f,0.f,0.f};
        for (int k0 = 0; k0 < 64; k0 += 32){
            s8v Bf[3];
            #pragma unroll
            for (int n = 0; n < 3; ++n) Bf[n] = *(const s8v*)(w1s + (n*16+l15)*72 + k0 + quad*8);
            #pragma unroll
            for (int i = 0; i < 3; ++i){
                int mt = wave + i*4;
                if (mt >= 9) break;
                s8v A = *(const s8v*)(ew2b + (mt*16 + l15)*64 + k0 + quad*8);
                #pragma unroll
                for (int n = 0; n < 3; ++n)
                    a2[i][n] = __builtin_amdgcn_mfma_f32_16x16x32_bf16(A, Bf[n], a2[i][n], 0, 0, 0);
            }
        }
        #pragma unroll
        for (int i = 0; i < 3; ++i){
            int mt = wave + i*4;
            if (mt >= 9) break;
            #pragma unroll
            for (int n = 0; n < 3; ++n)
                #pragma unroll
                for (int reg = 0; reg < 4; ++reg){
                    int o = mt*16 + quad*4 + reg;
                    int px = n*16 + l15;
                    float val = (a2[i][n][reg] + eb2f[o])*wsc[o] + wbi[o];
                    int g = o/9, t = o - g*9;
                    int tr3 = (t >= 3) + (t >= 6);       // row of tap
                    int tc = t - tr3*3;                  // col of tap
                    int gcol = px0 + px;
                    bool kill = (r == 0 && tr3 == 0) || (r == 95 && tr3 == 2)
                             || (gcol == 0 && tc == 0) || (gcol == 95 && tc == 2);
                    w2s[g*576 + px*12 + t] = kill ? (short)0 : f2bs(val);
                }
        }
    }
    __syncthreads();   // w1s dead; w2s ready
    if (tid < 128){ bns[tid] = 0.f; bnq[tid] = 0.f; }
    __syncthreads();
    // ---- local conv: 9 offset loads from one base address, weights pre-masked; BN accum ----
    const short* vb = (const short*)vbuf;
    long base0 = (long)b*CD*HW + (long)(r - 1)*WD + (px0 - 1);
    for (int it = tid; it < 6144; it += 256){
        int c = it / 48, px = it - c*48;
        const short* wp = w2s + (c>>3)*576 + px*12;
        s4vv wA = *(const s4vv*)wp;        // taps 0..3
        s4vv wB = *(const s4vv*)(wp + 4);  // taps 4..7
        float w8 = bs2f(wp[8]);
        const short* vp = vb + base0 + (long)c*HW + px;
        float acc;
        acc  = bs2f(vp[0])   * bs2f(wA[0]);
        acc += bs2f(vp[1])   * bs2f(wA[1]);
        acc += bs2f(vp[2])   * bs2f(wA[2]);
        acc += bs2f(vp[96])  * bs2f(wA[3]);
        acc += bs2f(vp[97])  * bs2f(wB[0]);
        acc += bs2f(vp[98])  * bs2f(wB[1]);
        acc += bs2f(vp[192]) * bs2f(wB[2]);
        acc += bs2f(vp[193]) * bs2f(wB[3]);
        acc += bs2f(vp[194]) * w8;
        yout[((size_t)b*CD + c)*HW + (size_t)r*WD + px0 + px] = acc;
        atomicAdd(&bns[c], acc);
        atomicAdd(&bnq[c], acc*acc);
    }
    __syncthreads();
    if (tid < 128){
        int slot = blk & 255;
        atomicAdd(&bnsum_s[tid*256 + slot], bns[tid]);
        atomicAdd(&bnss_s [tid*256 + slot], bnq[tid]);
    }
}

// ================= FALLBACK (R6 embed) =================
template<bool APPLY>
__global__ void k_embed_mfma(const void* __restrict__ x, const int* __restrict__ flags,
                             const bf16* __restrict__ kbuf, const short* __restrict__ canonb,
                             const float* __restrict__ canonf,
                             const float* __restrict__ gmean, const float* __restrict__ gistd,
                             const bf16* __restrict__ vbuf, float* __restrict__ yout,
                             float* __restrict__ gsum_s, float* __restrict__ gsq_s,
                             float* __restrict__ bnsum_s, float* __restrict__ bnss_s){
    __shared__ char buf0[26624];
    __shared__ short w1s[48*72];
    __shared__ short w2s[48*152];
    __shared__ float wsc[WC], wbi[WC];
    __shared__ float blks[256], blkq[256];
    short* qk = (short*)buf0;
    float* yt = (float*)buf0;
    const short* ew1b = canonb + BO_EW1;
    const short* ew2b = canonb + BO_EW2;
    const float* eb2f = canonf + CO_EB2;
    int blk = blockIdx.x;
    int px0 = (blk & 1)*48, r = (blk >> 1) % 96, b = blk / 192;
    int tid = threadIdx.x;
    bool F = flags[0] != 0;
    if (APPLY && tid < WC){
        int g = tid/9;
        float m = gmean[b*NG+g], is = gistd[b*NG+g];
        float ga = canonf[CO_GNG + tid], be = canonf[CO_GNB + tid];
        wsc[tid] = is*ga; wbi[tid] = be - m*is*ga;
    }
    for (int idx = tid; idx < 128*48; idx += 256){
        int c = idx / 48, px = idx - c*48;
        size_t off = ((size_t)b*CD + c)*HW + r*WD + px0 + px;
        float v = F ? ((const float*)x)[off] : b2f(((const bf16*)x)[off]);
        qk[px*264 + c] = f2bs(v);
    }
    for (int idx = tid; idx < 128*48; idx += 256){
        int c = idx / 48, px = idx - c*48;
        qk[px*264 + 128 + c] = ((const short*)kbuf)[((size_t)b*CD + c)*HW + r*WD + px0 + px];
    }
    __syncthreads();
    int wave = tid >> 6, lane = tid & 63, l15 = lane & 15, quad = lane >> 4;
    {
        f4v a1[3];
        #pragma unroll
        for (int n = 0; n < 3; ++n) a1[n] = (f4v){0.f,0.f,0.f,0.f};
        int mb = wave*16;
        for (int k0 = 0; k0 < 256; k0 += 32){
            s8v A = *(const s8v*)(ew1b + (mb + l15)*256 + k0 + quad*8);
            #pragma unroll
            for (int n = 0; n < 3; ++n){
                s8v Bf = *(const s8v*)(qk + (n*16+l15)*264 + k0 + quad*8);
                a1[n] = __builtin_amdgcn_mfma_f32_16x16x32_bf16(A, Bf, a1[n], 0, 0, 0);
            }
        }
        __syncthreads();
        #pragma unroll
        for (int n = 0; n < 3; ++n)
            #pragma unroll
            for (int reg = 0; reg < 4; ++reg){
                int ch = mb + quad*4 + reg;
                int px = n*16 + l15;
                w1s[px*72 + ch] = f2bs(fmaxf(a1[n][reg], 0.f));
            }
    }
    __syncthreads();
    {
        f4v a2[3][3];
        #pragma unroll
        for (int i = 0; i < 3; ++i)
            #pragma unroll
            for (int n = 0; n < 3; ++n) a2[i][n] = (f4v){0.f,0.f,0.f,0.f};
        for (int k0 = 0; k0 < 64; k0 += 32){
            s8v Bf[3];
            #pragma unroll
            for (int n = 0; n < 3; ++n) Bf[n] = *(const s8v*)(w1s + (n*16+l15)*72 + k0 + quad*8);
            #pragma unroll
            for (int i = 0; i < 3; ++i){
                int mt = wave + i*4;
                if (mt >= 9) break;
                s8v A = *(const s8v*)(ew2b + (mt*16 + l15)*64 + k0 + quad*8);
                #pragma unroll
                for (int n = 0; n < 3; ++n)
                    a2[i][n] = __builtin_amdgcn_mfma_f32_16x16x32_bf16(A, Bf[n], a2[i][n], 0, 0, 0);
            }
        }
        #pragma unroll
        for (int i = 0; i < 3; ++i){
            int mt = wave + i*4;
            if (mt >= 9) break;
            #pragma unroll
            for (int n = 0; n < 3; ++n)
                #pragma unroll
                for (int reg = 0; reg < 4; ++reg){
                    int o = mt*16 + quad*4 + reg;
                    int px = n*16 + l15;
                    float val = a2[i][n][reg] + eb2f[o];
                    if (APPLY) val = val*wsc[o] + wbi[o];
                    w2s[px*152 + o] = f2bs(val);
                }
        }
    }
    __syncthreads();
    if (!APPLY){
        if (tid < WC){
            int o = tid; float s = 0.f, ss = 0.f;
            for (int px = 0; px < 48; ++px){ float v = bs2f(w2s[px*152+o]); s += v; ss += v*v; }
            int g = o/9; int slot = blk & 63;
            atomicAdd(&gsum_s[(b*NG+g)*64 + slot], s);
            atomicAdd(&gsq_s [(b*NG+g)*64 + slot], ss);
        }
        return;
    }
    if (tid < 192){
        int px = tid % 48, cq = tid / 48;
        int gcol = px0 + px;
        for (int c = cq*32; c < cq*32 + 32; ++c){
            int g9 = (c >> 3)*9;
            const bf16* vb = vbuf + ((size_t)b*CD + c)*HW;
            float acc = 0.f;
            #pragma unroll
            for (int t = 0; t < 9; ++t){
                int ir = r + t/3 - 1, icc = gcol + t%3 - 1;
                if ((unsigned)ir < 96u && (unsigned)icc < 96u)
                    acc += b2f(vb[ir*WD + icc]) * bs2f(w2s[px*152 + g9 + t]);
            }
            yt[c*52 + px] = acc;
        }
    }
    __syncthreads();
    {
        int c = tid & 127, half = tid >> 7;
        float s = 0.f, ss = 0.f;
        for (int px = half*24; px < half*24 + 24; ++px){
            float v = yt[c*52 + px]; s += v; ss += v*v;
        }
        blks[tid] = s; blkq[tid] = ss;
    }
    __syncthreads();
    if (tid < 128){
        float s = blks[tid] + blks[tid+128];
        float ss = blkq[tid] + blkq[tid+128];
        int slot = blk & 255;
        atomicAdd(&bnsum_s[tid*256 + slot], s);
        atomicAdd(&bnss_s [tid*256 + slot], ss);
    }
    for (int idx = tid; idx < 128*48; idx += 256){
        int c = idx / 48, px = idx - c*48;
        yout[((size_t)b*CD + c)*HW + r*WD + px0 + px] = yt[c*52 + px];
    }
}

// ---------------- GN finalize ----------------
__global__ void k_gnfin(const float* __restrict__ gsum_s, const float* __restrict__ gsq_s,
                        float* __restrict__ gmean, float* __restrict__ gistd){
    int i = threadIdx.x;
    float s = 0.f, ss = 0.f;
    for (int k = 0; k < 64; ++k){ s += gsum_s[i*64 + k]; ss += gsq_s[i*64 + k]; }
    float inv = 1.f / (9.f*HW);
    float m = s*inv;
    float var = ss*inv - m*m;
    gmean[i] = m;
    gistd[i] = rsqrtf(var + 1e-5f);
}

// ---------------- BN finalize ----------------
__global__ void k_bnfin(const float* __restrict__ bnsum_s, const float* __restrict__ bnss_s,
                        const float* __restrict__ canonf,
                        float* __restrict__ scale, float* __restrict__ shift){
    int c = threadIdx.x;
    float s = 0.f, ss = 0.f;
    for (int k = 0; k < 256; ++k){ s += bnsum_s[c*256 + k]; ss += bnss_s[c*256 + k]; }
    float inv = 1.f / (float)(BD*HW);
    float m = s*inv;
    float var = ss*inv - m*m;
    float sc = canonf[CO_BNG + c] * rsqrtf(var + 1e-5f);
    scale[c] = sc;
    shift[c] = canonf[CO_BNB + c] - m*sc;
}

// ---------------- GAP: Sum swish(bn(y)) only; Sum(k) pre-accumulated by keyconv ----------------
__global__ void k_gap(const float* __restrict__ ybuf,
                      const float* __restrict__ scale, const float* __restrict__ shift,
                      float* __restrict__ gap){
    int blk = blockIdx.x;            // 1024 = 8b x 128c
    int bc = (blk & 7)*CD + (blk >> 3);
    int c = bc % CD;
    int tid = threadIdx.x;
    float sc = scale[c], sh = shift[c];
    const float4* y4 = (const float4*)ybuf + (size_t)bc*2304;
    float gs = 0.f;
    for (int k = 0; k < 9; ++k){
        float4 yv = y4[k*256 + tid];
        #pragma unroll
        for (int j = 0; j < 4; ++j){
            float yn = ((&yv.x)[j])*sc + sh;
            gs += yn / (1.f + __expf(-yn));
        }
    }
    __shared__ float shm[256];
    shm[tid] = gs; __syncthreads();
    for (int st = 128; st > 0; st >>= 1){
        if (tid < st) shm[tid] += shm[tid+st];
        __syncthreads();
    }
    if (tid == 0) gap[bc] += shm[0];
}

// ---------------- SE ----------------
__global__ void k_se(const float* __restrict__ gap, const float* __restrict__ canonf,
                     float* __restrict__ p0, float* __restrict__ p1){
    int b = blockIdx.x;
    int tid = threadIdx.x;
    __shared__ float loc[128], h1[64];
    float invhw = 1.f / (float)HW;
    loc[tid]      = gap[b*CD + tid]      * invhw;
    loc[tid + 64] = gap[b*CD + tid + 64] * invhw;
    __syncthreads();
    {
        const float* wr = canonf + CO_SW1 + (size_t)tid*128;
        float acc = canonf[CO_SB1 + tid];
        for (int c = 0; c < 128; ++c) acc += wr[c] * loc[c];
        h1[tid] = fmaxf(acc, 0.f);
    }
    __syncthreads();
    for (int c = tid; c < 128; c += 64){
        float a0 = canonf[CO_SB2 + 2*c], a1 = canonf[CO_SB2 + 2*c+1];
        const float* w0 = canonf + CO_SW2 + (size_t)(2*c)*64;
        const float* w1p = canonf + CO_SW2 + (size_t)(2*c+1)*64;
        for (int j = 0; j < 64; ++j){
            a0 += w0[j] * h1[j];
            a1 += w1p[j] * h1[j];
        }
        float mx = fmaxf(a0, a1);
        float e0 = __expf(a0-mx), e1 = __expf(a1-mx);
        float inv = 1.f / (e0 + e1);
        p0[b*CD+c] = e0*inv;
        p1[b*CD+c] = e1*inv;
    }
}

// ---------------- out: float4 recompute BN+swish, blend, in-place (b-locked XCD swizzle) ----------------
__global__ void k_out(float* __restrict__ ybuf, const bf16* __restrict__ kbuf,
                      const float* __restrict__ scale, const float* __restrict__ shift,
                      const float* __restrict__ p0, const float* __restrict__ p1){
    int blk = blockIdx.x;                              // 9216 = 8b x 1152
    size_t idx = ((size_t)((blk & 7)*1152 + (blk >> 3)))*256 + threadIdx.x;
    int bc = (int)(idx / 2304);
    int c = bc % CD;
    float sc = scale[c], sh = shift[c];
    float q0 = p0[bc], q1 = p1[bc];
    float4 yv = ((const float4*)ybuf)[idx];
    ushort4 kv = ((const ushort4*)kbuf)[idx];
    float4 ov;
    #pragma unroll
    for (int j = 0; j < 4; ++j){
        float yn = ((&yv.x)[j])*sc + sh;
        float ys = yn / (1.f + __expf(-yn));
        (&ov.x)[j] = ys*q0 + bs2f((short)((&kv.x)[j]))*q1;
    }
    ((float4*)ybuf)[idx] = ov;
}

extern "C" void kernel_launch(void* const* d_in, const int* in_sizes, int n_in,
                              void* d_out, int out_size, void* d_ws, size_t ws_size,
                              hipStream_t stream) {
    TensPtrs tp;
    for (int i = 0; i < 14; ++i) tp.p[i] = d_in[i];

    float* f = (float*)d_ws;
    float* bnsum_s = f;            // 32768 (zeroed)
    float* bnss_s  = f + 32768;    // 32768 (zeroed)
    float* gsum_s  = f + 65536;    // 8192  (zeroed)
    float* gsq_s   = f + 73728;    // 8192  (zeroed)
    float* gap     = f + 81920;    // 1024  (zeroed; keyconv accumulates Sum(k) here)
    float* gmean   = f + 82944;
    float* gistd   = f + 83072;
    float* bscale  = f + 83200;
    float* bshift  = f + 83328;
    float* p0      = f + 83456;
    float* p1      = f + 84480;
    int*   flags = (int*)((char*)d_ws + 393216);
    float* canonf = (float*)((char*)d_ws + 425984);
    short* canonb = (short*)((char*)d_ws + 860160);
    bf16*  kbuf  = (bf16*)((char*)d_ws + 1048576);        // 18.87 MB
    bf16*  vbuf  = kbuf + NTOT;                           // 18.87 MB (ends 38,797,312)
    unsigned short* w1b = (unsigned short*)((char*)d_ws + 38797312);  // 9.44 MB (ends 48,234,496)
    float* ybuf  = (float*)d_out;
    short* kwre = (short*)((char*)d_out + KWRE_OFF);      // d_out scratch (pre-y)
    unsigned short* xb16 = (unsigned short*)d_out;        // d_out scratch [0,18.9MB) (f32-x case only)

    bool fast = ws_size >= 48234496ull;

    k_detect<<<14, 256, 0, stream>>>(tp, flags);
    k_canon<<<208, 256, 0, stream>>>(tp, flags, canonf, canonb);
    k_zero<<<324, 256, 0, stream>>>(f, 82944);
    k_xcast<<<1024, 256, 0, stream>>>(d_in[0], flags, xb16);
    k_reorder_kw<<<144, 256, 0, stream>>>(canonb, kwre);
    k_keyconv_mfma<<<768, 256, 0, stream>>>((const short*)xb16, (const short*)d_in[0],
                                            flags, kwre, kbuf, gap);
    if (fast){
        k_embed_stats<<<1536, 256, 0, stream>>>((const short*)xb16, (const short*)d_in[0],
                                                flags, kbuf, canonb, canonf,
                                                w1b, vbuf, gsum_s, gsq_s);
        k_gnfin<<<1, 128, 0, stream>>>(gsum_s, gsq_s, gmean, gistd);
        k_embed_apply<<<1536, 256, 0, stream>>>(w1b, canonb, canonf, gmean, gistd,
                                                vbuf, ybuf, bnsum_s, bnss_s);
    } else {
        k_embed_mfma<false><<<1536, 256, 0, stream>>>(d_in[0], flags, kbuf, canonb, canonf,
                                                      gmean, gistd, vbuf, ybuf,
                                                      gsum_s, gsq_s, bnsum_s, bnss_s);
        k_gnfin<<<1, 128, 0, stream>>>(gsum_s, gsq_s, gmean, gistd);
        k_vconv_mfma<<<768, 256, 0, stream>>>(d_in[0], flags, canonb, vbuf);
        k_embed_mfma<true><<<1536, 256, 0, stream>>>(d_in[0], flags, kbuf, canonb, canonf,
                                                     gmean, gistd, vbuf, ybuf,
                                                     gsum_s, gsq_s, bnsum_s, bnss_s);
    }
    k_bnfin<<<1, 128, 0, stream>>>(bnsum_s, bnss_s, canonf, bscale, bshift);
    k_gap<<<1024, 256, 0, stream>>>(ybuf, bscale, bshift, gap);
    k_se<<<BD, 64, 0, stream>>>(gap, canonf, p0, p1);
    k_out<<<(int)(NTOT/4/256), 256, 0, stream>>>(ybuf, kbuf, bscale, bshift, p0, p1);
}

// Round 6
// 275.132 us; speedup vs baseline: 1.3632x; 1.3632x over previous
//
#include <hip/hip_runtime.h>
#include <hip/hip_bf16.h>

#define BD 8
#define CD 128
#define HD 96
#define WD 96
#define HW (HD*WD)          // 9216
#define NPIX (BD*HW)        // 73728
#define NTOT ((size_t)BD*CD*HW) // 9437184
#define WC 144
#define NG 16
#define KWRE_OFF 37617664   // scratch inside d_out (y overwrites it later)
// xb16 (bf16 x) lives at d_out[0 .. 18.9MB) during the front half; y overwrites later.

typedef __hip_bfloat16 bf16;
typedef __attribute__((ext_vector_type(8))) short s8v;   // 8 bf16 (A/B frag)
typedef __attribute__((ext_vector_type(4))) float f4v;   // 4 f32 (C/D frag)
typedef __attribute__((ext_vector_type(4))) short s4vv;  // 4 bf16 (8B LDS read)

__device__ __forceinline__ float b2f(bf16 v){ return __bfloat162float(v); }
__device__ __forceinline__ bf16  f2b(float v){ return __float2bfloat16(v); }
__device__ __forceinline__ short f2bs(float f){ union{ bf16 h; short s; } u; u.h = f2b(f); return u.s; }
__device__ __forceinline__ float bs2f(short s){ union{ bf16 h; short s; } u; u.s = s; return b2f(u.h); }

struct TensPtrs { const void* p[14]; };

__device__ __constant__ int dNelem[14] = {
    9437184, 36864, 16384, 9216, 144, 144, 144, 16384, 128, 128, 8192, 64, 16384, 256
};
__device__ __constant__ int dCanonOff[14] = {
    0, 0, 36864, 53248, 62464, 62608, 62752, 62896, 79280, 79408, 79536, 87728, 87792, 104176
};
__device__ __constant__ int dBOff[14] = {
    -1, 0, 36864, 53248, -1, -1, -1, 62464, -1, -1, -1, -1, -1, -1
};
#define CO_EB2  62464
#define CO_GNG  62608
#define CO_GNB  62752
#define CO_BNG  79280
#define CO_BNB  79408
#define CO_SW1  79536
#define CO_SB1  87728
#define CO_SW2  87792
#define CO_SB2  104176
#define BO_KW   0
#define BO_EW1  36864
#define BO_EW2  53248
#define BO_C1W  62464

// swizzled LDS address helpers: byte ^= ((px>>3)&7)<<4  (breaks 8-px-stride bank aliasing)
__device__ __forceinline__ char* qk_sw(short* base, int px, int e){
    return (char*)base + ((((px*136 + e)*2)) ^ (((px>>3)&7)<<4));
}
__device__ __forceinline__ char* xt_sw(short* base, int px, int e){
    return (char*)base + (((px*32 + e)*2) ^ (((px>>3)&7)<<4));
}
// pack a ch-pair column into pixel-major LDS
__device__ __forceinline__ void qk_write(short* qk, int p8, int c, s8v t0, s8v t1){
    #pragma unroll
    for (int jj = 0; jj < 8; ++jj){
        int px = p8*8 + jj;
        unsigned int pk = (unsigned int)(unsigned short)t0[jj]
                        | ((unsigned int)(unsigned short)t1[jj] << 16);
        *(unsigned int*)qk_sw(qk, px, c) = pk;
    }
}

// ---------------- detect (256 threads, 4B pair loads) ----------------
__global__ void k_detect(TensPtrs tp, int* __restrict__ flags){
    int i = blockIdx.x; int tid = threadIdx.x;
    int n = dNelem[i];
    int m = n < 4096 ? n : 4096;
    int pairs = m >> 1;
    const unsigned int* u = (const unsigned int*)tp.p[i];
    int v = 0;
    for (int j = tid; j < pairs; j += 256){
        unsigned int w = u[j];
        unsigned short lo = (unsigned short)(w & 0xffff);
        unsigned short hi = (unsigned short)(w >> 16);
        int e = (lo >> 7) & 0xFF;
        bool wild = (e >= 0xBE) || (e > 0 && e < 0x40);
        if (wild || (lo == 0 && hi != 0)) v++;
    }
    __shared__ int sv[256];
    sv[tid] = v; __syncthreads();
    for (int st = 128; st > 0; st >>= 1){
        if (tid < st) sv[tid] += sv[tid+st];
        __syncthreads();
    }
    if (tid == 0) flags[i] = (sv[0]*8 > pairs) ? 1 : 0;
}

// ---------------- canon (16 chunk-blocks per tensor) ----------------
__global__ void k_canon(TensPtrs tp, const int* __restrict__ flags,
                        float* __restrict__ canonf, short* __restrict__ canonb){
    int i = (blockIdx.x >> 4) + 1;            // 13 tensors x 16 chunks
    int chunk = blockIdx.x & 15;
    int n = dNelem[i]; int off = dCanonOff[i]; int bo = dBOff[i];
    bool f32 = flags[i] != 0;
    for (int j = chunk*256 + threadIdx.x; j < n; j += 4096){
        float v = f32 ? ((const float*)tp.p[i])[j] : b2f(((const bf16*)tp.p[i])[j]);
        canonf[off + j] = v;
        if (bo >= 0) canonb[bo + j] = f2bs(v);
    }
}

// ---------------- xcast: only needed for f32 x; bf16 x is consumed in place ----------------
__global__ void k_xcast(const void* __restrict__ x, const int* __restrict__ flags,
                        unsigned short* __restrict__ xb){
    if (!flags[0]) return;                    // bf16 input: consumers read x directly
    int blk = blockIdx.x;                     // 1024 = 8b x 128; 2304 vec4 each
    size_t base = ((size_t)((blk & 7)*128 + (blk >> 3)))*2304;
    for (int k = 0; k < 9; ++k){
        size_t i = base + k*256 + threadIdx.x;
        float4 v = ((const float4*)x)[i];
        ushort4 o;
        o.x = (unsigned short)f2bs(v.x); o.y = (unsigned short)f2bs(v.y);
        o.z = (unsigned short)f2bs(v.z); o.w = (unsigned short)f2bs(v.w);
        ((ushort4*)xb)[i] = o;
    }
}

// ---------------- reorder key weights: [g][oc][ic][t] -> [g][t][oc][ic] ----------------
__global__ void k_reorder_kw(const short* __restrict__ canonb, short* __restrict__ kwre){
    int idx = blockIdx.x*256 + threadIdx.x;   // 36864
    if (idx >= 36864) return;
    int g = idx / 9216, rem = idx - g*9216;
    int oc = rem / 288, r2 = rem - oc*288;
    int ic = r2 / 9, t = r2 - ic*9;
    kwre[g*9216 + t*1024 + oc*32 + ic] = canonb[BO_KW + idx];
}

__global__ void k_zero(float* __restrict__ p, int n){
    int i = blockIdx.x*256 + threadIdx.x;
    if (i < n) p[i] = 0.f;
}

// ---------------- keyconv MFMA (+fused Sum(relu k) for SE gap; b-locked XCD swizzle) ----------------
__global__ void k_keyconv_mfma(const short* __restrict__ xb, const short* __restrict__ xorig,
                               const int* __restrict__ flags,
                               const short* __restrict__ kwre, bf16* __restrict__ kout,
                               float* __restrict__ kgap){
    __shared__ short xt[588*32];     // [pixel(6x98)][ic], XOR-swizzled bytes, 37632 B
    int blk = blockIdx.x;            // 768 = 8b x 96(j)
    int b = blk & 7, j = blk >> 3;
    int band = j % 24, g = j / 24;
    int r0 = band*4;
    int tid = threadIdx.x;
    const short* xs = flags[0] ? xb : xorig;
    // interior pixels (icol 0..95) : 6 rows x 16 ch-pairs x 12 groups of 8 px
    for (int idx = tid; idx < 1152; idx += 256){
        int pr = idx / 192, rem = idx - pr*192;
        int c2 = rem / 12, gx = rem - c2*12;
        int ir = r0 - 1 + pr;
        int c = c2*2;
        s8v t0 = (s8v){0,0,0,0,0,0,0,0};
        s8v t1 = (s8v){0,0,0,0,0,0,0,0};
        if ((unsigned)ir < 96u){
            size_t gb = ((size_t)b*CD + g*32 + c)*HW + (size_t)ir*WD + gx*8;
            t0 = *(const s8v*)(xs + gb);
            t1 = *(const s8v*)(xs + gb + HW);
        }
        #pragma unroll
        for (int jj = 0; jj < 8; ++jj){
            int pxl = pr*98 + gx*8 + 1 + jj;
            unsigned int pk = (unsigned int)(unsigned short)t0[jj]
                            | ((unsigned int)(unsigned short)t1[jj] << 16);
            *(unsigned int*)xt_sw(xt, pxl, c) = pk;
        }
    }
    // edge columns pc=0 (icol=-1) and pc=97 (icol=96): zero
    for (int idx = tid; idx < 192; idx += 256){
        int pr = idx / 32, rem = idx - pr*32;
        int e = rem >> 4, c2 = rem & 15;
        int pxl = pr*98 + (e ? 97 : 0);
        *(unsigned int*)xt_sw(xt, pxl, c2*2) = 0u;
    }
    __syncthreads();
    int wave = tid >> 6, lane = tid & 63, l15 = lane & 15, quad = lane >> 4;
    f4v acc[2][6];
    #pragma unroll
    for (int m = 0; m < 2; ++m)
        #pragma unroll
        for (int n = 0; n < 6; ++n) acc[m][n] = (f4v){0.f,0.f,0.f,0.f};
    const short* kg = kwre + g*9216;
    for (int t = 0; t < 9; ++t){
        s8v A0 = *(const s8v*)(kg + t*1024 + l15*32 + quad*8);
        s8v A1 = *(const s8v*)(kg + t*1024 + (16+l15)*32 + quad*8);
        int pbase = (wave + t/3)*98 + (t%3) + l15;
        #pragma unroll
        for (int n = 0; n < 6; ++n){
            int pxl = pbase + n*16;
            s8v B = *(const s8v*)xt_sw(xt, pxl, quad*8);
            acc[0][n] = __builtin_amdgcn_mfma_f32_16x16x32_bf16(A0, B, acc[0][n], 0, 0, 0);
            acc[1][n] = __builtin_amdgcn_mfma_f32_16x16x32_bf16(A1, B, acc[1][n], 0, 0, 0);
        }
    }
    int r = r0 + wave;
    #pragma unroll
    for (int m = 0; m < 2; ++m)
        #pragma unroll
        for (int n = 0; n < 6; ++n)
            #pragma unroll
            for (int reg = 0; reg < 4; ++reg){
                int oc = g*32 + m*16 + quad*4 + reg;
                int px = n*16 + l15;
                kout[((size_t)b*CD + oc)*HW + r*WD + px] = f2b(fmaxf(acc[m][n][reg], 0.f));
            }
    // fused Sum(relu k) over this block's 4 rows x 96 px per oc -> SE gap accumulator
    #pragma unroll
    for (int m = 0; m < 2; ++m)
        #pragma unroll
        for (int reg = 0; reg < 4; ++reg){
            float s = 0.f;
            #pragma unroll
            for (int n = 0; n < 6; ++n) s += fmaxf(acc[m][n][reg], 0.f);
            #pragma unroll
            for (int off = 1; off < 16; off <<= 1) s += __shfl_xor(s, off);
            if (l15 == 0){
                int oc = g*32 + m*16 + quad*4 + reg;
                atomicAdd(&kgap[b*CD + oc], s);
            }
        }
}

// ---------------- vconv MFMA (fallback path only) ----------------
__global__ void k_vconv_mfma(const void* __restrict__ x, const int* __restrict__ flags,
                             const short* __restrict__ c1wb, bf16* __restrict__ vout){
    __shared__ short xt[96*136];
    int blk = blockIdx.x; int b = blk / 96, r = blk % 96;
    int tid = threadIdx.x;
    bool F = flags[0] != 0;
    for (int idx = tid; idx < 1536; idx += 256){
        int oct = idx / 96, px = idx - oct*96;
        size_t base = ((size_t)b*CD + oct*8)*HW + r*WD + px;
        s8v tmp;
        #pragma unroll
        for (int j = 0; j < 8; ++j){
            float v = F ? ((const float*)x)[base + (size_t)j*HW]
                        : b2f(((const bf16*)x)[base + (size_t)j*HW]);
            tmp[j] = f2bs(v);
        }
        *(s8v*)(xt + px*136 + oct*8) = tmp;
    }
    __syncthreads();
    int wave = tid >> 6, lane = tid & 63, l15 = lane & 15, quad = lane >> 4;
    f4v acc[2][6];
    #pragma unroll
    for (int m = 0; m < 2; ++m)
        #pragma unroll
        for (int n = 0; n < 6; ++n) acc[m][n] = (f4v){0.f,0.f,0.f,0.f};
    for (int k0 = 0; k0 < 128; k0 += 32){
        s8v Bf[6];
        #pragma unroll
        for (int n = 0; n < 6; ++n) Bf[n] = *(const s8v*)(xt + (n*16+l15)*136 + k0 + quad*8);
        #pragma unroll
        for (int m = 0; m < 2; ++m){
            int oc0 = (wave*2 + m)*16;
            s8v A = *(const s8v*)(c1wb + BO_C1W + (oc0 + l15)*128 + k0 + quad*8);
            #pragma unroll
            for (int n = 0; n < 6; ++n)
                acc[m][n] = __builtin_amdgcn_mfma_f32_16x16x32_bf16(A, Bf[n], acc[m][n], 0, 0, 0);
        }
    }
    #pragma unroll
    for (int m = 0; m < 2; ++m)
        #pragma unroll
        for (int n = 0; n < 6; ++n)
            #pragma unroll
            for (int reg = 0; reg < 4; ++reg){
                int oc = (wave*2+m)*16 + quad*4 + reg;
                int px = n*16 + l15;
                vout[((size_t)b*CD + oc)*HW + r*WD + px] = f2b(acc[m][n][reg]);
            }
}

// ================= FAST PATH =================
// embed STATS + fused vconv; k-half register-prefetch (T14); b-locked XCD swizzle
__global__ void k_embed_stats(const short* __restrict__ xb, const short* __restrict__ xorig,
                              const int* __restrict__ flags,
                              const bf16* __restrict__ kbuf, const short* __restrict__ canonb,
                              const float* __restrict__ canonf,
                              unsigned short* __restrict__ w1b, bf16* __restrict__ vout,
                              float* __restrict__ gsum_s, float* __restrict__ gsq_s){
    __shared__ short qk[48*136];     // 13056 B, XOR-swizzled, one 128-ch half at a time
    __shared__ short w1s[48*72];     // 6912 B
    __shared__ float gacc[16], gacc2[16];
    const short* ew1b = canonb + BO_EW1;
    const short* ew2b = canonb + BO_EW2;
    const float* eb2f = canonf + CO_EB2;
    int blk = blockIdx.x;            // 1536 = 8b x 192(j)
    int b = blk & 7, j = blk >> 3;
    int px0 = (j & 1)*48, r = j >> 1;
    int tid = threadIdx.x;
    int wave = tid >> 6, lane = tid & 63, l15 = lane & 15, quad = lane >> 4;
    const short* xs = flags[0] ? xb : xorig;
    const short* kb = (const short*)kbuf;
    if (tid < 16){ gacc[tid] = 0.f; gacc2[tid] = 0.f; }
    // ---- per-thread staging coords: item A = tid (all), item B = 256+tid (tid<128) ----
    int c2a = tid / 6, p8a = tid - c2a*6;
    size_t gba = ((size_t)b*CD + c2a*2)*HW + r*WD + px0 + p8a*8;
    bool has2 = tid < 128;
    int ib = 256 + tid;
    int c2b = ib / 6, p8b = ib - c2b*6;
    size_t gbb = ((size_t)b*CD + c2b*2)*HW + r*WD + px0 + p8b*8;
    // issue ALL loads up front: x half + k half (k stays in regs until after vconv)
    s8v xa0 = *(const s8v*)(xs + gba);
    s8v xa1 = *(const s8v*)(xs + gba + HW);
    s8v ka0 = *(const s8v*)(kb + gba);
    s8v ka1 = *(const s8v*)(kb + gba + HW);
    s8v xb0, xb1, kb0, kb1;
    if (has2){
        xb0 = *(const s8v*)(xs + gbb);
        xb1 = *(const s8v*)(xs + gbb + HW);
        kb0 = *(const s8v*)(kb + gbb);
        kb1 = *(const s8v*)(kb + gbb + HW);
    }
    // write x to LDS
    qk_write(qk, p8a, c2a*2, xa0, xa1);
    if (has2) qk_write(qk, p8b, c2b*2, xb0, xb1);
    __syncthreads();
    // ---- GEMM1 half 1 ----
    f4v a1[3];
    #pragma unroll
    for (int n = 0; n < 3; ++n) a1[n] = (f4v){0.f,0.f,0.f,0.f};
    int mb = wave*16;
    for (int k0 = 0; k0 < 128; k0 += 32){
        s8v A = *(const s8v*)(ew1b + (mb + l15)*256 + k0 + quad*8);
        #pragma unroll
        for (int n = 0; n < 3; ++n){
            int px = n*16 + l15;
            s8v Bf = *(const s8v*)qk_sw(qk, px, k0 + quad*8);
            a1[n] = __builtin_amdgcn_mfma_f32_16x16x32_bf16(A, Bf, a1[n], 0, 0, 0);
        }
    }
    // ---- fused vconv GEMM: v[128 x 48] = C1W[128x128] * X[128x48] ----
    {
        f4v av[2][3];
        #pragma unroll
        for (int m = 0; m < 2; ++m)
            #pragma unroll
            for (int n = 0; n < 3; ++n) av[m][n] = (f4v){0.f,0.f,0.f,0.f};
        for (int k0 = 0; k0 < 128; k0 += 32){
            s8v Bf[3];
            #pragma unroll
            for (int n = 0; n < 3; ++n){
                int px = n*16 + l15;
                Bf[n] = *(const s8v*)qk_sw(qk, px, k0 + quad*8);
            }
            #pragma unroll
            for (int m = 0; m < 2; ++m){
                int oc0 = (wave*2 + m)*16;
                s8v A = *(const s8v*)(canonb + BO_C1W + (oc0 + l15)*128 + k0 + quad*8);
                #pragma unroll
                for (int n = 0; n < 3; ++n)
                    av[m][n] = __builtin_amdgcn_mfma_f32_16x16x32_bf16(A, Bf[n], av[m][n], 0, 0, 0);
            }
        }
        #pragma unroll
        for (int m = 0; m < 2; ++m)
            #pragma unroll
            for (int n = 0; n < 3; ++n)
                #pragma unroll
                for (int reg = 0; reg < 4; ++reg){
                    int oc = (wave*2+m)*16 + quad*4 + reg;
                    int px = n*16 + l15;
                    vout[((size_t)b*CD + oc)*HW + r*WD + px0 + px] = f2b(av[m][n][reg]);
                }
    }
    __syncthreads();
    // ---- write prefetched k half to LDS (loads long since landed) ----
    qk_write(qk, p8a, c2a*2, ka0, ka1);
    if (has2) qk_write(qk, p8b, c2b*2, kb0, kb1);
    __syncthreads();
    for (int k0 = 128; k0 < 256; k0 += 32){
        s8v A = *(const s8v*)(ew1b + (mb + l15)*256 + k0 + quad*8);
        #pragma unroll
        for (int n = 0; n < 3; ++n){
            int px = n*16 + l15;
            s8v Bf = *(const s8v*)qk_sw(qk, px, (k0-128) + quad*8);
            a1[n] = __builtin_amdgcn_mfma_f32_16x16x32_bf16(A, Bf, a1[n], 0, 0, 0);
        }
    }
    #pragma unroll
    for (int n = 0; n < 3; ++n)
        #pragma unroll
        for (int reg = 0; reg < 4; ++reg){
            int ch = mb + quad*4 + reg;
            int px = n*16 + l15;
            w1s[px*72 + ch] = f2bs(fmaxf(a1[n][reg], 0.f));
        }
    __syncthreads();
    size_t gpx0 = (size_t)b*HW + r*WD + px0;
    for (int idx = tid; idx < 768; idx += 256){
        int px = idx >> 4, s4 = idx & 15;
        ushort4 v4 = *(const ushort4*)((const unsigned short*)w1s + px*72 + s4*4);
        *(ushort4*)(w1b + (gpx0 + px)*64 + s4*4) = v4;
    }
    // ---- GEMM2 + frag-level GN moment reduction ----
    {
        f4v a2[3][3];
        #pragma unroll
        for (int i = 0; i < 3; ++i)
            #pragma unroll
            for (int n = 0; n < 3; ++n) a2[i][n] = (f4v){0.f,0.f,0.f,0.f};
        for (int k0 = 0; k0 < 64; k0 += 32){
            s8v Bf[3];
            #pragma unroll
            for (int n = 0; n < 3; ++n) Bf[n] = *(const s8v*)(w1s + (n*16+l15)*72 + k0 + quad*8);
            #pragma unroll
            for (int i = 0; i < 3; ++i){
                int mt = wave + i*4;
                if (mt >= 9) break;
                s8v A = *(const s8v*)(ew2b + (mt*16 + l15)*64 + k0 + quad*8);
                #pragma unroll
                for (int n = 0; n < 3; ++n)
                    a2[i][n] = __builtin_amdgcn_mfma_f32_16x16x32_bf16(A, Bf[n], a2[i][n], 0, 0, 0);
            }
        }
        #pragma unroll
        for (int i = 0; i < 3; ++i){
            int mt = wave + i*4;
            if (mt >= 9) break;
            #pragma unroll
            for (int n = 0; n < 3; ++n)
                #pragma unroll
                for (int reg = 0; reg < 4; ++reg){
                    int o = mt*16 + quad*4 + reg;
                    float v = a2[i][n][reg] + eb2f[o];
                    float s = v, q = v*v;
                    #pragma unroll
                    for (int off = 1; off < 16; off <<= 1){
                        s += __shfl_xor(s, off);
                        q += __shfl_xor(q, off);
                    }
                    if (l15 == 0){
                        int g = o / 9;
                        atomicAdd(&gacc[g], s);
                        atomicAdd(&gacc2[g], q);
                    }
                }
        }
    }
    __syncthreads();
    if (tid < 16){
        int slot = j & 63;
        atomicAdd(&gsum_s[(b*NG + tid)*64 + slot], gacc[tid]);
        atomicAdd(&gsq_s [(b*NG + tid)*64 + slot], gacc2[tid]);
    }
}

// ---------------- embed APPLY (R10 proven form: edge-masked w2, offset-load conv) ----------------
__global__ void k_embed_apply(const unsigned short* __restrict__ w1b,
                              const short* __restrict__ canonb, const float* __restrict__ canonf,
                              const float* __restrict__ gmean, const float* __restrict__ gistd,
                              const bf16* __restrict__ vbuf, float* __restrict__ yout){
    __shared__ short w2s[9216];               // 18432 B  [g(16)][px(48)][12] tap-major
    __shared__ short w1s[48*72];              // 6912 B
    __shared__ float wsc[WC], wbi[WC];        // 1152 B
    const short* ew2b = canonb + BO_EW2;
    const float* eb2f = canonf + CO_EB2;
    int blk = blockIdx.x;                     // 1536 = 8b x 192(j)
    int b = blk & 7, j = blk >> 3;
    int px0 = (j & 1)*48, r = j >> 1;
    int tid = threadIdx.x;
    int wave = tid >> 6, lane = tid & 63, l15 = lane & 15, quad = lane >> 4;
    if (tid < WC){
        int g = tid/9;
        float m = gmean[b*NG+g], is = gistd[b*NG+g];
        float ga = canonf[CO_GNG + tid], be = canonf[CO_GNB + tid];
        wsc[tid] = is*ga; wbi[tid] = be - m*is*ga;
    }
    size_t gpx0 = (size_t)b*HW + r*WD + px0;
    for (int idx = tid; idx < 768; idx += 256){
        int px = idx >> 4, s4 = idx & 15;
        ushort4 v4 = *(const ushort4*)(w1b + (gpx0 + px)*64 + s4*4);
        *(ushort4*)((unsigned short*)w1s + px*72 + s4*4) = v4;
    }
    __syncthreads();
    // ---- GEMM2 -> GN-applied, edge-masked, tap-major w2s ----
    {
        f4v a2[3][3];
        #pragma unroll
        for (int i = 0; i < 3; ++i)
            #pragma unroll
            for (int n = 0; n < 3; ++n) a2[i][n] = (f4v){0.f,0.f,0.f,0.f};
        for (int k0 = 0; k0 < 64; k0 += 32){
            s8v Bf[3];
            #pragma unroll
            for (int n = 0; n < 3; ++n) Bf[n] = *(const s8v*)(w1s + (n*16+l15)*72 + k0 + quad*8);
            #pragma unroll
            for (int i = 0; i < 3; ++i){
                int mt = wave + i*4;
                if (mt >= 9) break;
                s8v A = *(const s8v*)(ew2b + (mt*16 + l15)*64 + k0 + quad*8);
                #pragma unroll
                for (int n = 0; n < 3; ++n)
                    a2[i][n] = __builtin_amdgcn_mfma_f32_16x16x32_bf16(A, Bf[n], a2[i][n], 0, 0, 0);
            }
        }
        #pragma unroll
        for (int i = 0; i < 3; ++i){
            int mt = wave + i*4;
            if (mt >= 9) break;
            #pragma unroll
            for (int n = 0; n < 3; ++n)
                #pragma unroll
                for (int reg = 0; reg < 4; ++reg){
                    int o = mt*16 + quad*4 + reg;
                    int px = n*16 + l15;
                    float val = (a2[i][n][reg] + eb2f[o])*wsc[o] + wbi[o];
                    int g = o/9, t = o - g*9;
                    int tr3 = (t >= 3) + (t >= 6);       // row of tap
                    int tc = t - tr3*3;                  // col of tap
                    int gcol = px0 + px;
                    bool kill = (r == 0 && tr3 == 0) || (r == 95 && tr3 == 2)
                             || (gcol == 0 && tc == 0) || (gcol == 95 && tc == 2);
                    w2s[g*576 + px*12 + t] = kill ? (short)0 : f2bs(val);
                }
        }
    }
    __syncthreads();
    // ---- local conv: 9 offset loads from one base address, weights pre-masked ----
    const short* vb = (const short*)vbuf;
    long base0 = (long)b*CD*HW + (long)(r - 1)*WD + (px0 - 1);
    for (int it = tid; it < 6144; it += 256){
        int c = it / 48, px = it - c*48;
        const short* wp = w2s + (c>>3)*576 + px*12;
        s4vv wA = *(const s4vv*)wp;        // taps 0..3
        s4vv wB = *(const s4vv*)(wp + 4);  // taps 4..7
        float w8 = bs2f(wp[8]);
        const short* vp = vb + base0 + (long)c*HW + px;
        float acc;
        acc  = bs2f(vp[0])   * bs2f(wA[0]);
        acc += bs2f(vp[1])   * bs2f(wA[1]);
        acc += bs2f(vp[2])   * bs2f(wA[2]);
        acc += bs2f(vp[96])  * bs2f(wA[3]);
        acc += bs2f(vp[97])  * bs2f(wB[0]);
        acc += bs2f(vp[98])  * bs2f(wB[1]);
        acc += bs2f(vp[192]) * bs2f(wB[2]);
        acc += bs2f(vp[193]) * bs2f(wB[3]);
        acc += bs2f(vp[194]) * w8;
        yout[((size_t)b*CD + c)*HW + (size_t)r*WD + px0 + px] = acc;
    }
}

// ---------------- BN stats from y (float4, 8 slices/channel) ----------------
__global__ void k_bnstat(const float* __restrict__ y, float* __restrict__ bnsum_s,
                         float* __restrict__ bnss_s){
    int blk = blockIdx.x;            // 1024 = 128c x 8 slices
    int c = blk >> 3, slice = blk & 7;
    int tid = threadIdx.x;
    const float4* y4 = (const float4*)y;
    float s = 0.f, ss = 0.f;
    int i0 = slice*2304;             // vec4 index within 18432 per channel
    for (int k = 0; k < 9; ++k){
        int i = i0 + k*256 + tid;    // i in [0, 18432)
        int b = i / 2304, p4 = i - b*2304;
        float4 v = y4[(size_t)(b*CD + c)*2304 + p4];
        s += v.x + v.y + v.z + v.w;
        ss += v.x*v.x + v.y*v.y + v.z*v.z + v.w*v.w;
    }
    __shared__ float sh[256], sh2[256];
    sh[tid] = s; sh2[tid] = ss;
    __syncthreads();
    for (int st = 128; st > 0; st >>= 1){
        if (tid < st){ sh[tid] += sh[tid+st]; sh2[tid] += sh2[tid+st]; }
        __syncthreads();
    }
    if (tid == 0){
        bnsum_s[c*256 + slice] = sh[0];
        bnss_s [c*256 + slice] = sh2[0];
    }
}

// ================= FALLBACK (R6 embed) =================
template<bool APPLY>
__global__ void k_embed_mfma(const void* __restrict__ x, const int* __restrict__ flags,
                             const bf16* __restrict__ kbuf, const short* __restrict__ canonb,
                             const float* __restrict__ canonf,
                             const float* __restrict__ gmean, const float* __restrict__ gistd,
                             const bf16* __restrict__ vbuf, float* __restrict__ yout,
                             float* __restrict__ gsum_s, float* __restrict__ gsq_s,
                             float* __restrict__ bnsum_s, float* __restrict__ bnss_s){
    __shared__ char buf0[26624];
    __shared__ short w1s[48*72];
    __shared__ short w2s[48*152];
    __shared__ float wsc[WC], wbi[WC];
    __shared__ float blks[256], blkq[256];
    short* qk = (short*)buf0;
    float* yt = (float*)buf0;
    const short* ew1b = canonb + BO_EW1;
    const short* ew2b = canonb + BO_EW2;
    const float* eb2f = canonf + CO_EB2;
    int blk = blockIdx.x;
    int px0 = (blk & 1)*48, r = (blk >> 1) % 96, b = blk / 192;
    int tid = threadIdx.x;
    bool F = flags[0] != 0;
    if (APPLY && tid < WC){
        int g = tid/9;
        float m = gmean[b*NG+g], is = gistd[b*NG+g];
        float ga = canonf[CO_GNG + tid], be = canonf[CO_GNB + tid];
        wsc[tid] = is*ga; wbi[tid] = be - m*is*ga;
    }
    for (int idx = tid; idx < 128*48; idx += 256){
        int c = idx / 48, px = idx - c*48;
        size_t off = ((size_t)b*CD + c)*HW + r*WD + px0 + px;
        float v = F ? ((const float*)x)[off] : b2f(((const bf16*)x)[off]);
        qk[px*264 + c] = f2bs(v);
    }
    for (int idx = tid; idx < 128*48; idx += 256){
        int c = idx / 48, px = idx - c*48;
        qk[px*264 + 128 + c] = ((const short*)kbuf)[((size_t)b*CD + c)*HW + r*WD + px0 + px];
    }
    __syncthreads();
    int wave = tid >> 6, lane = tid & 63, l15 = lane & 15, quad = lane >> 4;
    {
        f4v a1[3];
        #pragma unroll
        for (int n = 0; n < 3; ++n) a1[n] = (f4v){0.f,0.f,0.f,0.f};
        int mb = wave*16;
        for (int k0 = 0; k0 < 256; k0 += 32){
            s8v A = *(const s8v*)(ew1b + (mb + l15)*256 + k0 + quad*8);
            #pragma unroll
            for (int n = 0; n < 3; ++n){
                s8v Bf = *(const s8v*)(qk + (n*16+l15)*264 + k0 + quad*8);
                a1[n] = __builtin_amdgcn_mfma_f32_16x16x32_bf16(A, Bf, a1[n], 0, 0, 0);
            }
        }
        __syncthreads();
        #pragma unroll
        for (int n = 0; n < 3; ++n)
            #pragma unroll
            for (int reg = 0; reg < 4; ++reg){
                int ch = mb + quad*4 + reg;
                int px = n*16 + l15;
                w1s[px*72 + ch] = f2bs(fmaxf(a1[n][reg], 0.f));
            }
    }
    __syncthreads();
    {
        f4v a2[3][3];
        #pragma unroll
        for (int i = 0; i < 3; ++i)
            #pragma unroll
            for (int n = 0; n < 3; ++n) a2[i][n] = (f4v){0.f,0.f,0.f,0.f};
        for (int k0 = 0; k0 < 64; k0 += 32){
            s8v Bf[3];
            #pragma unroll
            for (int n = 0; n < 3; ++n) Bf[n] = *(const s8v*)(w1s + (n*16+l15)*72 + k0 + quad*8);
            #pragma unroll
            for (int i = 0; i < 3; ++i){
                int mt = wave + i*4;
                if (mt >= 9) break;
                s8v A = *(const s8v*)(ew2b + (mt*16 + l15)*64 + k0 + quad*8);
                #pragma unroll
                for (int n = 0; n < 3; ++n)
                    a2[i][n] = __builtin_amdgcn_mfma_f32_16x16x32_bf16(A, Bf[n], a2[i][n], 0, 0, 0);
            }
        }
        #pragma unroll
        for (int i = 0; i < 3; ++i){
            int mt = wave + i*4;
            if (mt >= 9) break;
            #pragma unroll
            for (int n = 0; n < 3; ++n)
                #pragma unroll
                for (int reg = 0; reg < 4; ++reg){
                    int o = mt*16 + quad*4 + reg;
                    int px = n*16 + l15;
                    float val = a2[i][n][reg] + eb2f[o];
                    if (APPLY) val = val*wsc[o] + wbi[o];
                    w2s[px*152 + o] = f2bs(val);
                }
        }
    }
    __syncthreads();
    if (!APPLY){
        if (tid < WC){
            int o = tid; float s = 0.f, ss = 0.f;
            for (int px = 0; px < 48; ++px){ float v = bs2f(w2s[px*152+o]); s += v; ss += v*v; }
            int g = o/9; int slot = blk & 63;
            atomicAdd(&gsum_s[(b*NG+g)*64 + slot], s);
            atomicAdd(&gsq_s [(b*NG+g)*64 + slot], ss);
        }
        return;
    }
    if (tid < 192){
        int px = tid % 48, cq = tid / 48;
        int gcol = px0 + px;
        for (int c = cq*32; c < cq*32 + 32; ++c){
            int g9 = (c >> 3)*9;
            const bf16* vb = vbuf + ((size_t)b*CD + c)*HW;
            float acc = 0.f;
            #pragma unroll
            for (int t = 0; t < 9; ++t){
                int ir = r + t/3 - 1, icc = gcol + t%3 - 1;
                if ((unsigned)ir < 96u && (unsigned)icc < 96u)
                    acc += b2f(vb[ir*WD + icc]) * bs2f(w2s[px*152 + g9 + t]);
            }
            yt[c*52 + px] = acc;
        }
    }
    __syncthreads();
    {
        int c = tid & 127, half = tid >> 7;
        float s = 0.f, ss = 0.f;
        for (int px = half*24; px < half*24 + 24; ++px){
            float v = yt[c*52 + px]; s += v; ss += v*v;
        }
        blks[tid] = s; blkq[tid] = ss;
    }
    __syncthreads();
    if (tid < 128){
        float s = blks[tid] + blks[tid+128];
        float ss = blkq[tid] + blkq[tid+128];
        int slot = blk & 255;
        atomicAdd(&bnsum_s[tid*256 + slot], s);
        atomicAdd(&bnss_s [tid*256 + slot], ss);
    }
    for (int idx = tid; idx < 128*48; idx += 256){
        int c = idx / 48, px = idx - c*48;
        yout[((size_t)b*CD + c)*HW + r*WD + px0 + px] = yt[c*52 + px];
    }
}

// ---------------- GN finalize ----------------
__global__ void k_gnfin(const float* __restrict__ gsum_s, const float* __restrict__ gsq_s,
                        float* __restrict__ gmean, float* __restrict__ gistd){
    int i = threadIdx.x;
    float s = 0.f, ss = 0.f;
    for (int k = 0; k < 64; ++k){ s += gsum_s[i*64 + k]; ss += gsq_s[i*64 + k]; }
    float inv = 1.f / (9.f*HW);
    float m = s*inv;
    float var = ss*inv - m*m;
    gmean[i] = m;
    gistd[i] = rsqrtf(var + 1e-5f);
}

// ---------------- BN finalize ----------------
__global__ void k_bnfin(const float* __restrict__ bnsum_s, const float* __restrict__ bnss_s,
                        const float* __restrict__ canonf,
                        float* __restrict__ scale, float* __restrict__ shift){
    int c = threadIdx.x;
    float s = 0.f, ss = 0.f;
    for (int k = 0; k < 256; ++k){ s += bnsum_s[c*256 + k]; ss += bnss_s[c*256 + k]; }
    float inv = 1.f / (float)(BD*HW);
    float m = s*inv;
    float var = ss*inv - m*m;
    float sc = canonf[CO_BNG + c] * rsqrtf(var + 1e-5f);
    scale[c] = sc;
    shift[c] = canonf[CO_BNB + c] - m*sc;
}

// ---------------- GAP: Sum swish(bn(y)) only; Sum(k) pre-accumulated by keyconv ----------------
__global__ void k_gap(const float* __restrict__ ybuf,
                      const float* __restrict__ scale, const float* __restrict__ shift,
                      float* __restrict__ gap){
    int blk = blockIdx.x;            // 1024 = 8b x 128c
    int bc = (blk & 7)*CD + (blk >> 3);
    int c = bc % CD;
    int tid = threadIdx.x;
    float sc = scale[c], sh = shift[c];
    const float4* y4 = (const float4*)ybuf + (size_t)bc*2304;
    float gs = 0.f;
    for (int k = 0; k < 9; ++k){
        float4 yv = y4[k*256 + tid];
        #pragma unroll
        for (int j = 0; j < 4; ++j){
            float yn = ((&yv.x)[j])*sc + sh;
            gs += yn / (1.f + __expf(-yn));
        }
    }
    __shared__ float shm[256];
    shm[tid] = gs; __syncthreads();
    for (int st = 128; st > 0; st >>= 1){
        if (tid < st) shm[tid] += shm[tid+st];
        __syncthreads();
    }
    if (tid == 0) gap[bc] += shm[0];
}

// ---------------- SE ----------------
__global__ void k_se(const float* __restrict__ gap, const float* __restrict__ canonf,
                     float* __restrict__ p0, float* __restrict__ p1){
    int b = blockIdx.x;
    int tid = threadIdx.x;
    __shared__ float loc[128], h1[64];
    float invhw = 1.f / (float)HW;
    loc[tid]      = gap[b*CD + tid]      * invhw;
    loc[tid + 64] = gap[b*CD + tid + 64] * invhw;
    __syncthreads();
    {
        const float* wr = canonf + CO_SW1 + (size_t)tid*128;
        float acc = canonf[CO_SB1 + tid];
        for (int c = 0; c < 128; ++c) acc += wr[c] * loc[c];
        h1[tid] = fmaxf(acc, 0.f);
    }
    __syncthreads();
    for (int c = tid; c < 128; c += 64){
        float a0 = canonf[CO_SB2 + 2*c], a1 = canonf[CO_SB2 + 2*c+1];
        const float* w0 = canonf + CO_SW2 + (size_t)(2*c)*64;
        const float* w1p = canonf + CO_SW2 + (size_t)(2*c+1)*64;
        for (int j = 0; j < 64; ++j){
            a0 += w0[j] * h1[j];
            a1 += w1p[j] * h1[j];
        }
        float mx = fmaxf(a0, a1);
        float e0 = __expf(a0-mx), e1 = __expf(a1-mx);
        float inv = 1.f / (e0 + e1);
        p0[b*CD+c] = e0*inv;
        p1[b*CD+c] = e1*inv;
    }
}

// ---------------- out: float4 recompute BN+swish, blend, in-place (b-locked XCD swizzle) ----------------
__global__ void k_out(float* __restrict__ ybuf, const bf16* __restrict__ kbuf,
                      const float* __restrict__ scale, const float* __restrict__ shift,
                      const float* __restrict__ p0, const float* __restrict__ p1){
    int blk = blockIdx.x;                              // 9216 = 8b x 1152
    size_t idx = ((size_t)((blk & 7)*1152 + (blk >> 3)))*256 + threadIdx.x;
    int bc = (int)(idx / 2304);
    int c = bc % CD;
    float sc = scale[c], sh = shift[c];
    float q0 = p0[bc], q1 = p1[bc];
    float4 yv = ((const float4*)ybuf)[idx];
    ushort4 kv = ((const ushort4*)kbuf)[idx];
    float4 ov;
    #pragma unroll
    for (int j = 0; j < 4; ++j){
        float yn = ((&yv.x)[j])*sc + sh;
        float ys = yn / (1.f + __expf(-yn));
        (&ov.x)[j] = ys*q0 + bs2f((short)((&kv.x)[j]))*q1;
    }
    ((float4*)ybuf)[idx] = ov;
}

extern "C" void kernel_launch(void* const* d_in, const int* in_sizes, int n_in,
                              void* d_out, int out_size, void* d_ws, size_t ws_size,
                              hipStream_t stream) {
    TensPtrs tp;
    for (int i = 0; i < 14; ++i) tp.p[i] = d_in[i];

    float* f = (float*)d_ws;
    float* bnsum_s = f;            // 32768 (zeroed)
    float* bnss_s  = f + 32768;    // 32768 (zeroed)
    float* gsum_s  = f + 65536;    // 8192  (zeroed)
    float* gsq_s   = f + 73728;    // 8192  (zeroed)
    float* gap     = f + 81920;    // 1024  (zeroed; keyconv accumulates Sum(k) here)
    float* gmean   = f + 82944;
    float* gistd   = f + 83072;
    float* bscale  = f + 83200;
    float* bshift  = f + 83328;
    float* p0      = f + 83456;
    float* p1      = f + 84480;
    int*   flags = (int*)((char*)d_ws + 393216);
    float* canonf = (float*)((char*)d_ws + 425984);
    short* canonb = (short*)((char*)d_ws + 860160);
    bf16*  kbuf  = (bf16*)((char*)d_ws + 1048576);        // 18.87 MB
    bf16*  vbuf  = kbuf + NTOT;                           // 18.87 MB (ends 38,797,312)
    unsigned short* w1b = (unsigned short*)((char*)d_ws + 38797312);  // 9.44 MB (ends 48,234,496)
    float* ybuf  = (float*)d_out;
    short* kwre = (short*)((char*)d_out + KWRE_OFF);      // d_out scratch (pre-y)
    unsigned short* xb16 = (unsigned short*)d_out;        // d_out scratch [0,18.9MB) (f32-x case only)

    bool fast = ws_size >= 48234496ull;

    k_detect<<<14, 256, 0, stream>>>(tp, flags);
    k_canon<<<208, 256, 0, stream>>>(tp, flags, canonf, canonb);
    k_zero<<<324, 256, 0, stream>>>(f, 82944);
    k_xcast<<<1024, 256, 0, stream>>>(d_in[0], flags, xb16);
    k_reorder_kw<<<144, 256, 0, stream>>>(canonb, kwre);
    k_keyconv_mfma<<<768, 256, 0, stream>>>((const short*)xb16, (const short*)d_in[0],
                                            flags, kwre, kbuf, gap);
    if (fast){
        k_embed_stats<<<1536, 256, 0, stream>>>((const short*)xb16, (const short*)d_in[0],
                                                flags, kbuf, canonb, canonf,
                                                w1b, vbuf, gsum_s, gsq_s);
        k_gnfin<<<1, 128, 0, stream>>>(gsum_s, gsq_s, gmean, gistd);
        k_embed_apply<<<1536, 256, 0, stream>>>(w1b, canonb, canonf, gmean, gistd,
                                                vbuf, ybuf);
        k_bnstat<<<1024, 256, 0, stream>>>(ybuf, bnsum_s, bnss_s);
    } else {
        k_embed_mfma<false><<<1536, 256, 0, stream>>>(d_in[0], flags, kbuf, canonb, canonf,
                                                      gmean, gistd, vbuf, ybuf,
                                                      gsum_s, gsq_s, bnsum_s, bnss_s);
        k_gnfin<<<1, 128, 0, stream>>>(gsum_s, gsq_s, gmean, gistd);
        k_vconv_mfma<<<768, 256, 0, stream>>>(d_in[0], flags, canonb, vbuf);
        k_embed_mfma<true><<<1536, 256, 0, stream>>>(d_in[0], flags, kbuf, canonb, canonf,
                                                     gmean, gistd, vbuf, ybuf,
                                                     gsum_s, gsq_s, bnsum_s, bnss_s);
    }
    k_bnfin<<<1, 128, 0, stream>>>(bnsum_s, bnss_s, canonf, bscale, bshift);
    k_gap<<<1024, 256, 0, stream>>>(ybuf, bscale, bshift, gap);
    k_se<<<BD, 64, 0, stream>>>(gap, canonf, p0, p1);
    k_out<<<(int)(NTOT/4/256), 256, 0, stream>>>(ybuf, kbuf, bscale, bshift, p0, p1);
}

// Round 9
// 259.089 us; speedup vs baseline: 1.4476x; 1.0619x over previous
//
#include <hip/hip_runtime.h>
#include <hip/hip_bf16.h>

#define BD 8
#define CD 128
#define HD 96
#define WD 96
#define HW (HD*WD)          // 9216
#define NPIX (BD*HW)        // 73728
#define NTOT ((size_t)BD*CD*HW) // 9437184
#define WC 144
#define NG 16
#define KWRE_OFF 37617664   // scratch inside d_out (y overwrites it later)
// xb16 (bf16 x) lives at d_out[0 .. 18.9MB) during the front half; y overwrites later.

typedef __hip_bfloat16 bf16;
typedef __attribute__((ext_vector_type(8))) short s8v;   // 8 bf16 (A/B frag)
typedef __attribute__((ext_vector_type(4))) float f4v;   // 4 f32 (C/D frag)
typedef __attribute__((ext_vector_type(4))) short s4vv;  // 4 bf16 (8B LDS read)

__device__ __forceinline__ float b2f(bf16 v){ return __bfloat162float(v); }
__device__ __forceinline__ bf16  f2b(float v){ return __float2bfloat16(v); }
__device__ __forceinline__ short f2bs(float f){ union{ bf16 h; short s; } u; u.h = f2b(f); return u.s; }
__device__ __forceinline__ float bs2f(short s){ union{ bf16 h; short s; } u; u.s = s; return b2f(u.h); }

struct TensPtrs { const void* p[14]; };

__device__ __constant__ int dNelem[14] = {
    9437184, 36864, 16384, 9216, 144, 144, 144, 16384, 128, 128, 8192, 64, 16384, 256
};
__device__ __constant__ int dCanonOff[14] = {
    0, 0, 36864, 53248, 62464, 62608, 62752, 62896, 79280, 79408, 79536, 87728, 87792, 104176
};
__device__ __constant__ int dBOff[14] = {
    -1, 0, 36864, 53248, -1, -1, -1, 62464, -1, -1, -1, -1, -1, -1
};
#define CO_EB2  62464
#define CO_GNG  62608
#define CO_GNB  62752
#define CO_BNG  79280
#define CO_BNB  79408
#define CO_SW1  79536
#define CO_SB1  87728
#define CO_SW2  87792
#define CO_SB2  104176
#define BO_KW   0
#define BO_EW1  36864
#define BO_EW2  53248
#define BO_C1W  62464

// swizzled LDS address helpers: byte ^= ((px>>3)&7)<<4  (breaks 8-px-stride bank aliasing)
__device__ __forceinline__ char* qk_sw(short* base, int px, int e){
    return (char*)base + ((((px*136 + e)*2)) ^ (((px>>3)&7)<<4));
}
__device__ __forceinline__ char* xt_sw(short* base, int px, int e){
    return (char*)base + (((px*32 + e)*2) ^ (((px>>3)&7)<<4));
}
// pack a ch-pair column into pixel-major LDS
__device__ __forceinline__ void qk_write(short* qk, int p8, int c, s8v t0, s8v t1){
    #pragma unroll
    for (int jj = 0; jj < 8; ++jj){
        int px = p8*8 + jj;
        unsigned int pk = (unsigned int)(unsigned short)t0[jj]
                        | ((unsigned int)(unsigned short)t1[jj] << 16);
        *(unsigned int*)qk_sw(qk, px, c) = pk;
    }
}

// ---------------- detect (256 threads, 4B pair loads) ----------------
__global__ void k_detect(TensPtrs tp, int* __restrict__ flags){
    int i = blockIdx.x; int tid = threadIdx.x;
    int n = dNelem[i];
    int m = n < 4096 ? n : 4096;
    int pairs = m >> 1;
    const unsigned int* u = (const unsigned int*)tp.p[i];
    int v = 0;
    for (int j = tid; j < pairs; j += 256){
        unsigned int w = u[j];
        unsigned short lo = (unsigned short)(w & 0xffff);
        unsigned short hi = (unsigned short)(w >> 16);
        int e = (lo >> 7) & 0xFF;
        bool wild = (e >= 0xBE) || (e > 0 && e < 0x40);
        if (wild || (lo == 0 && hi != 0)) v++;
    }
    __shared__ int sv[256];
    sv[tid] = v; __syncthreads();
    for (int st = 128; st > 0; st >>= 1){
        if (tid < st) sv[tid] += sv[tid+st];
        __syncthreads();
    }
    if (tid == 0) flags[i] = (sv[0]*8 > pairs) ? 1 : 0;
}

// ---------------- canon (16 chunk-blocks per tensor) ----------------
__global__ void k_canon(TensPtrs tp, const int* __restrict__ flags,
                        float* __restrict__ canonf, short* __restrict__ canonb){
    int i = (blockIdx.x >> 4) + 1;            // 13 tensors x 16 chunks
    int chunk = blockIdx.x & 15;
    int n = dNelem[i]; int off = dCanonOff[i]; int bo = dBOff[i];
    bool f32 = flags[i] != 0;
    for (int j = chunk*256 + threadIdx.x; j < n; j += 4096){
        float v = f32 ? ((const float*)tp.p[i])[j] : b2f(((const bf16*)tp.p[i])[j]);
        canonf[off + j] = v;
        if (bo >= 0) canonb[bo + j] = f2bs(v);
    }
}

// ---------------- xcast: only needed for f32 x; bf16 x is consumed in place ----------------
__global__ void k_xcast(const void* __restrict__ x, const int* __restrict__ flags,
                        unsigned short* __restrict__ xb){
    if (!flags[0]) return;                    // bf16 input: consumers read x directly
    int blk = blockIdx.x;                     // 1024 = 8b x 128; 2304 vec4 each
    size_t base = ((size_t)((blk & 7)*128 + (blk >> 3)))*2304;
    for (int k = 0; k < 9; ++k){
        size_t i = base + k*256 + threadIdx.x;
        float4 v = ((const float4*)x)[i];
        ushort4 o;
        o.x = (unsigned short)f2bs(v.x); o.y = (unsigned short)f2bs(v.y);
        o.z = (unsigned short)f2bs(v.z); o.w = (unsigned short)f2bs(v.w);
        ((ushort4*)xb)[i] = o;
    }
}

// ---------------- reorder key weights: [g][oc][ic][t] -> [g][t][oc][ic] ----------------
__global__ void k_reorder_kw(const short* __restrict__ canonb, short* __restrict__ kwre){
    int idx = blockIdx.x*256 + threadIdx.x;   // 36864
    if (idx >= 36864) return;
    int g = idx / 9216, rem = idx - g*9216;
    int oc = rem / 288, r2 = rem - oc*288;
    int ic = r2 / 9, t = r2 - ic*9;
    kwre[g*9216 + t*1024 + oc*32 + ic] = canonb[BO_KW + idx];
}

__global__ void k_zero(float* __restrict__ p, int n){
    int i = blockIdx.x*256 + threadIdx.x;
    if (i < n) p[i] = 0.f;
}

// ---------------- keyconv MFMA (+fused Sum(relu k) for SE gap; b-locked XCD swizzle) ----------------
__global__ void k_keyconv_mfma(const short* __restrict__ xb, const short* __restrict__ xorig,
                               const int* __restrict__ flags,
                               const short* __restrict__ kwre, bf16* __restrict__ kout,
                               float* __restrict__ kgap){
    __shared__ short xt[588*32];     // [pixel(6x98)][ic], XOR-swizzled bytes, 37632 B
    int blk = blockIdx.x;            // 768 = 8b x 96(j)
    int b = blk & 7, j = blk >> 3;
    int band = j % 24, g = j / 24;
    int r0 = band*4;
    int tid = threadIdx.x;
    const short* xs = flags[0] ? xb : xorig;
    // interior pixels (icol 0..95) : 6 rows x 16 ch-pairs x 12 groups of 8 px
    for (int idx = tid; idx < 1152; idx += 256){
        int pr = idx / 192, rem = idx - pr*192;
        int c2 = rem / 12, gx = rem - c2*12;
        int ir = r0 - 1 + pr;
        int c = c2*2;
        s8v t0 = (s8v){0,0,0,0,0,0,0,0};
        s8v t1 = (s8v){0,0,0,0,0,0,0,0};
        if ((unsigned)ir < 96u){
            size_t gb = ((size_t)b*CD + g*32 + c)*HW + (size_t)ir*WD + gx*8;
            t0 = *(const s8v*)(xs + gb);
            t1 = *(const s8v*)(xs + gb + HW);
        }
        #pragma unroll
        for (int jj = 0; jj < 8; ++jj){
            int pxl = pr*98 + gx*8 + 1 + jj;
            unsigned int pk = (unsigned int)(unsigned short)t0[jj]
                            | ((unsigned int)(unsigned short)t1[jj] << 16);
            *(unsigned int*)xt_sw(xt, pxl, c) = pk;
        }
    }
    // edge columns pc=0 (icol=-1) and pc=97 (icol=96): zero
    for (int idx = tid; idx < 192; idx += 256){
        int pr = idx / 32, rem = idx - pr*32;
        int e = rem >> 4, c2 = rem & 15;
        int pxl = pr*98 + (e ? 97 : 0);
        *(unsigned int*)xt_sw(xt, pxl, c2*2) = 0u;
    }
    __syncthreads();
    int wave = tid >> 6, lane = tid & 63, l15 = lane & 15, quad = lane >> 4;
    f4v acc[2][6];
    #pragma unroll
    for (int m = 0; m < 2; ++m)
        #pragma unroll
        for (int n = 0; n < 6; ++n) acc[m][n] = (f4v){0.f,0.f,0.f,0.f};
    const short* kg = kwre + g*9216;
    for (int t = 0; t < 9; ++t){
        s8v A0 = *(const s8v*)(kg + t*1024 + l15*32 + quad*8);
        s8v A1 = *(const s8v*)(kg + t*1024 + (16+l15)*32 + quad*8);
        int pbase = (wave + t/3)*98 + (t%3) + l15;
        #pragma unroll
        for (int n = 0; n < 6; ++n){
            int pxl = pbase + n*16;
            s8v B = *(const s8v*)xt_sw(xt, pxl, quad*8);
            acc[0][n] = __builtin_amdgcn_mfma_f32_16x16x32_bf16(A0, B, acc[0][n], 0, 0, 0);
            acc[1][n] = __builtin_amdgcn_mfma_f32_16x16x32_bf16(A1, B, acc[1][n], 0, 0, 0);
        }
    }
    int r = r0 + wave;
    #pragma unroll
    for (int m = 0; m < 2; ++m)
        #pragma unroll
        for (int n = 0; n < 6; ++n)
            #pragma unroll
            for (int reg = 0; reg < 4; ++reg){
                int oc = g*32 + m*16 + quad*4 + reg;
                int px = n*16 + l15;
                kout[((size_t)b*CD + oc)*HW + r*WD + px] = f2b(fmaxf(acc[m][n][reg], 0.f));
            }
    // fused Sum(relu k) over this block's 4 rows x 96 px per oc -> SE gap accumulator
    #pragma unroll
    for (int m = 0; m < 2; ++m)
        #pragma unroll
        for (int reg = 0; reg < 4; ++reg){
            float s = 0.f;
            #pragma unroll
            for (int n = 0; n < 6; ++n) s += fmaxf(acc[m][n][reg], 0.f);
            #pragma unroll
            for (int off = 1; off < 16; off <<= 1) s += __shfl_xor(s, off);
            if (l15 == 0){
                int oc = g*32 + m*16 + quad*4 + reg;
                atomicAdd(&kgap[b*CD + oc], s);
            }
        }
}

// ---------------- vconv MFMA (fallback path only) ----------------
__global__ void k_vconv_mfma(const void* __restrict__ x, const int* __restrict__ flags,
                             const short* __restrict__ c1wb, bf16* __restrict__ vout){
    __shared__ short xt[96*136];
    int blk = blockIdx.x; int b = blk / 96, r = blk % 96;
    int tid = threadIdx.x;
    bool F = flags[0] != 0;
    for (int idx = tid; idx < 1536; idx += 256){
        int oct = idx / 96, px = idx - oct*96;
        size_t base = ((size_t)b*CD + oct*8)*HW + r*WD + px;
        s8v tmp;
        #pragma unroll
        for (int j = 0; j < 8; ++j){
            float v = F ? ((const float*)x)[base + (size_t)j*HW]
                        : b2f(((const bf16*)x)[base + (size_t)j*HW]);
            tmp[j] = f2bs(v);
        }
        *(s8v*)(xt + px*136 + oct*8) = tmp;
    }
    __syncthreads();
    int wave = tid >> 6, lane = tid & 63, l15 = lane & 15, quad = lane >> 4;
    f4v acc[2][6];
    #pragma unroll
    for (int m = 0; m < 2; ++m)
        #pragma unroll
        for (int n = 0; n < 6; ++n) acc[m][n] = (f4v){0.f,0.f,0.f,0.f};
    for (int k0 = 0; k0 < 128; k0 += 32){
        s8v Bf[6];
        #pragma unroll
        for (int n = 0; n < 6; ++n) Bf[n] = *(const s8v*)(xt + (n*16+l15)*136 + k0 + quad*8);
        #pragma unroll
        for (int m = 0; m < 2; ++m){
            int oc0 = (wave*2 + m)*16;
            s8v A = *(const s8v*)(c1wb + BO_C1W + (oc0 + l15)*128 + k0 + quad*8);
            #pragma unroll
            for (int n = 0; n < 6; ++n)
                acc[m][n] = __builtin_amdgcn_mfma_f32_16x16x32_bf16(A, Bf[n], acc[m][n], 0, 0, 0);
        }
    }
    #pragma unroll
    for (int m = 0; m < 2; ++m)
        #pragma unroll
        for (int n = 0; n < 6; ++n)
            #pragma unroll
            for (int reg = 0; reg < 4; ++reg){
                int oc = (wave*2+m)*16 + quad*4 + reg;
                int px = n*16 + l15;
                vout[((size_t)b*CD + oc)*HW + r*WD + px] = f2b(acc[m][n][reg]);
            }
}

// ================= FAST PATH =================
// embed STATS + fused vconv (R12-proven staging, no prefetch; b-locked XCD swizzle)
__global__ void k_embed_stats(const short* __restrict__ xb, const short* __restrict__ xorig,
                              const int* __restrict__ flags,
                              const bf16* __restrict__ kbuf, const short* __restrict__ canonb,
                              const float* __restrict__ canonf,
                              unsigned short* __restrict__ w1b, bf16* __restrict__ vout,
                              float* __restrict__ gsum_s, float* __restrict__ gsq_s){
    __shared__ short qk[48*136];
    __shared__ short w1s[48*72];
    __shared__ float gacc[16], gacc2[16];
    const short* ew1b = canonb + BO_EW1;
    const short* ew2b = canonb + BO_EW2;
    const float* eb2f = canonf + CO_EB2;
    int blk = blockIdx.x;            // 1536 = 8b x 192(j)
    int b = blk & 7, j = blk >> 3;
    int px0 = (j & 1)*48, r = j >> 1;
    int tid = threadIdx.x;
    int wave = tid >> 6, lane = tid & 63, l15 = lane & 15, quad = lane >> 4;
    const short* xs = flags[0] ? xb : xorig;
    const short* kb = (const short*)kbuf;
    if (tid < 16){ gacc[tid] = 0.f; gacc2[tid] = 0.f; }
    for (int idx = tid; idx < 384; idx += 256){
        int c2 = idx / 6, p8 = idx - c2*6;
        size_t gb = ((size_t)b*CD + c2*2)*HW + r*WD + px0 + p8*8;
        s8v t0 = *(const s8v*)(xs + gb);
        s8v t1 = *(const s8v*)(xs + gb + HW);
        qk_write(qk, p8, c2*2, t0, t1);
    }
    __syncthreads();
    f4v a1[3];
    #pragma unroll
    for (int n = 0; n < 3; ++n) a1[n] = (f4v){0.f,0.f,0.f,0.f};
    int mb = wave*16;
    for (int k0 = 0; k0 < 128; k0 += 32){
        s8v A = *(const s8v*)(ew1b + (mb + l15)*256 + k0 + quad*8);
        #pragma unroll
        for (int n = 0; n < 3; ++n){
            s8v Bf = *(const s8v*)qk_sw(qk, n*16+l15, k0 + quad*8);
            a1[n] = __builtin_amdgcn_mfma_f32_16x16x32_bf16(A, Bf, a1[n], 0, 0, 0);
        }
    }
    {
        f4v av[2][3];
        #pragma unroll
        for (int m = 0; m < 2; ++m)
            #pragma unroll
            for (int n = 0; n < 3; ++n) av[m][n] = (f4v){0.f,0.f,0.f,0.f};
        for (int k0 = 0; k0 < 128; k0 += 32){
            s8v Bf[3];
            #pragma unroll
            for (int n = 0; n < 3; ++n) Bf[n] = *(const s8v*)qk_sw(qk, n*16+l15, k0 + quad*8);
            #pragma unroll
            for (int m = 0; m < 2; ++m){
                int oc0 = (wave*2 + m)*16;
                s8v A = *(const s8v*)(canonb + BO_C1W + (oc0 + l15)*128 + k0 + quad*8);
                #pragma unroll
                for (int n = 0; n < 3; ++n)
                    av[m][n] = __builtin_amdgcn_mfma_f32_16x16x32_bf16(A, Bf[n], av[m][n], 0, 0, 0);
            }
        }
        #pragma unroll
        for (int m = 0; m < 2; ++m)
            #pragma unroll
            for (int n = 0; n < 3; ++n)
                #pragma unroll
                for (int reg = 0; reg < 4; ++reg){
                    int oc = (wave*2+m)*16 + quad*4 + reg;
                    int px = n*16 + l15;
                    vout[((size_t)b*CD + oc)*HW + r*WD + px0 + px] = f2b(av[m][n][reg]);
                }
    }
    __syncthreads();
    for (int idx = tid; idx < 384; idx += 256){
        int c2 = idx / 6, p8 = idx - c2*6;
        size_t gb = ((size_t)b*CD + c2*2)*HW + r*WD + px0 + p8*8;
        s8v t0 = *(const s8v*)(kb + gb);
        s8v t1 = *(const s8v*)(kb + gb + HW);
        qk_write(qk, p8, c2*2, t0, t1);
    }
    __syncthreads();
    for (int k0 = 128; k0 < 256; k0 += 32){
        s8v A = *(const s8v*)(ew1b + (mb + l15)*256 + k0 + quad*8);
        #pragma unroll
        for (int n = 0; n < 3; ++n){
            s8v Bf = *(const s8v*)qk_sw(qk, n*16+l15, (k0-128) + quad*8);
            a1[n] = __builtin_amdgcn_mfma_f32_16x16x32_bf16(A, Bf, a1[n], 0, 0, 0);
        }
    }
    #pragma unroll
    for (int n = 0; n < 3; ++n)
        #pragma unroll
        for (int reg = 0; reg < 4; ++reg){
            int ch = mb + quad*4 + reg;
            int px = n*16 + l15;
            w1s[px*72 + ch] = f2bs(fmaxf(a1[n][reg], 0.f));
        }
    __syncthreads();
    size_t gpx0 = (size_t)b*HW + r*WD + px0;
    for (int idx = tid; idx < 768; idx += 256){
        int px = idx >> 4, s4 = idx & 15;
        ushort4 v4 = *(const ushort4*)((const unsigned short*)w1s + px*72 + s4*4);
        *(ushort4*)(w1b + (gpx0 + px)*64 + s4*4) = v4;
    }
    {
        f4v a2[3][3];
        #pragma unroll
        for (int i = 0; i < 3; ++i)
            #pragma unroll
            for (int n = 0; n < 3; ++n) a2[i][n] = (f4v){0.f,0.f,0.f,0.f};
        for (int k0 = 0; k0 < 64; k0 += 32){
            s8v Bf[3];
            #pragma unroll
            for (int n = 0; n < 3; ++n) Bf[n] = *(const s8v*)(w1s + (n*16+l15)*72 + k0 + quad*8);
            #pragma unroll
            for (int i = 0; i < 3; ++i){
                int mt = wave + i*4;
                if (mt >= 9) break;
                s8v A = *(const s8v*)(ew2b + (mt*16 + l15)*64 + k0 + quad*8);
                #pragma unroll
                for (int n = 0; n < 3; ++n)
                    a2[i][n] = __builtin_amdgcn_mfma_f32_16x16x32_bf16(A, Bf[n], a2[i][n], 0, 0, 0);
            }
        }
        #pragma unroll
        for (int i = 0; i < 3; ++i){
            int mt = wave + i*4;
            if (mt >= 9) break;
            #pragma unroll
            for (int n = 0; n < 3; ++n)
                #pragma unroll
                for (int reg = 0; reg < 4; ++reg){
                    int o = mt*16 + quad*4 + reg;
                    float v = a2[i][n][reg] + eb2f[o];
                    float s = v, q = v*v;
                    #pragma unroll
                    for (int off = 1; off < 16; off <<= 1){
                        s += __shfl_xor(s, off);
                        q += __shfl_xor(q, off);
                    }
                    if (l15 == 0){
                        int g = o / 9;
                        atomicAdd(&gacc[g], s);
                        atomicAdd(&gacc2[g], q);
                    }
                }
        }
    }
    __syncthreads();
    if (tid < 16){
        int slot = j & 63;
        atomicAdd(&gsum_s[(b*NG + tid)*64 + slot], gacc[tid]);
        atomicAdd(&gsq_s [(b*NG + tid)*64 + slot], gacc2[tid]);
    }
}

// ---------------- embed APPLY (R10 conv + inline GN finalize; b-locked XCD swizzle) ----------------
__global__ void k_embed_apply(const unsigned short* __restrict__ w1b,
                              const short* __restrict__ canonb, const float* __restrict__ canonf,
                              const float* __restrict__ gsum_s, const float* __restrict__ gsq_s,
                              const bf16* __restrict__ vbuf, float* __restrict__ yout){
    __shared__ short w2s[9216];               // 18432 B  [g(16)][px(48)][12] tap-major
    __shared__ short w1s[48*72];              // 6912 B
    __shared__ float wsc[WC], wbi[WC];        // 1152 B
    __shared__ float gm[16], gi[16];          // 128 B (total 26752 -> still 6 blk/CU)
    const short* ew2b = canonb + BO_EW2;
    const float* eb2f = canonf + CO_EB2;
    int blk = blockIdx.x;                     // 1536 = 8b x 192(j)
    int b = blk & 7, j = blk >> 3;
    int px0 = (j & 1)*48, r = j >> 1;
    int tid = threadIdx.x;
    int wave = tid >> 6, lane = tid & 63, l15 = lane & 15, quad = lane >> 4;
    // ---- inline GN finalize (replaces k_gnfin): 16 groups x 16 slots x 4 sums ----
    {
        int g16 = tid >> 4, sl = tid & 15;
        int base = (b*NG + g16)*64 + sl*4;
        float s = 0.f, q = 0.f;
        #pragma unroll
        for (int t = 0; t < 4; ++t){ s += gsum_s[base+t]; q += gsq_s[base+t]; }
        #pragma unroll
        for (int off = 1; off < 16; off <<= 1){
            s += __shfl_xor(s, off);
            q += __shfl_xor(q, off);
        }
        if (sl == 0){
            float inv = 1.f / (9.f*HW);
            float m = s*inv;
            float var = q*inv - m*m;
            gm[g16] = m;
            gi[g16] = rsqrtf(var + 1e-5f);
        }
    }
    size_t gpx0 = (size_t)b*HW + r*WD + px0;
    for (int idx = tid; idx < 768; idx += 256){
        int px = idx >> 4, s4 = idx & 15;
        ushort4 v4 = *(const ushort4*)(w1b + (gpx0 + px)*64 + s4*4);
        *(ushort4*)((unsigned short*)w1s + px*72 + s4*4) = v4;
    }
    __syncthreads();
    if (tid < WC){
        int g = tid/9;
        float m = gm[g], is = gi[g];
        float ga = canonf[CO_GNG + tid], be = canonf[CO_GNB + tid];
        wsc[tid] = is*ga; wbi[tid] = be - m*is*ga;
    }
    __syncthreads();
    // ---- GEMM2 -> GN-applied, edge-masked, tap-major w2s ----
    {
        f4v a2[3][3];
        #pragma unroll
        for (int i = 0; i < 3; ++i)
            #pragma unroll
            for (int n = 0; n < 3; ++n) a2[i][n] = (f4v){0.f,0.f,0.f,0.f};
        for (int k0 = 0; k0 < 64; k0 += 32){
            s8v Bf[3];
            #pragma unroll
            for (int n = 0; n < 3; ++n) Bf[n] = *(const s8v*)(w1s + (n*16+l15)*72 + k0 + quad*8);
            #pragma unroll
            for (int i = 0; i < 3; ++i){
                int mt = wave + i*4;
                if (mt >= 9) break;
                s8v A = *(const s8v*)(ew2b + (mt*16 + l15)*64 + k0 + quad*8);
                #pragma unroll
                for (int n = 0; n < 3; ++n)
                    a2[i][n] = __builtin_amdgcn_mfma_f32_16x16x32_bf16(A, Bf[n], a2[i][n], 0, 0, 0);
            }
        }
        #pragma unroll
        for (int i = 0; i < 3; ++i){
            int mt = wave + i*4;
            if (mt >= 9) break;
            #pragma unroll
            for (int n = 0; n < 3; ++n)
                #pragma unroll
                for (int reg = 0; reg < 4; ++reg){
                    int o = mt*16 + quad*4 + reg;
                    int px = n*16 + l15;
                    float val = (a2[i][n][reg] + eb2f[o])*wsc[o] + wbi[o];
                    int g = o/9, t = o - g*9;
                    int tr3 = (t >= 3) + (t >= 6);       // row of tap
                    int tc = t - tr3*3;                  // col of tap
                    int gcol = px0 + px;
                    bool kill = (r == 0 && tr3 == 0) || (r == 95 && tr3 == 2)
                             || (gcol == 0 && tc == 0) || (gcol == 95 && tc == 2);
                    w2s[g*576 + px*12 + t] = kill ? (short)0 : f2bs(val);
                }
        }
    }
    __syncthreads();
    // ---- local conv: 9 offset loads from one base address, weights pre-masked ----
    const short* vb = (const short*)vbuf;
    long base0 = (long)b*CD*HW + (long)(r - 1)*WD + (px0 - 1);
    for (int it = tid; it < 6144; it += 256){
        int c = it / 48, px = it - c*48;
        const short* wp = w2s + (c>>3)*576 + px*12;
        s4vv wA = *(const s4vv*)wp;        // taps 0..3
        s4vv wB = *(const s4vv*)(wp + 4);  // taps 4..7
        float w8 = bs2f(wp[8]);
        const short* vp = vb + base0 + (long)c*HW + px;
        float acc;
        acc  = bs2f(vp[0])   * bs2f(wA[0]);
        acc += bs2f(vp[1])   * bs2f(wA[1]);
        acc += bs2f(vp[2])   * bs2f(wA[2]);
        acc += bs2f(vp[96])  * bs2f(wA[3]);
        acc += bs2f(vp[97])  * bs2f(wB[0]);
        acc += bs2f(vp[98])  * bs2f(wB[1]);
        acc += bs2f(vp[192]) * bs2f(wB[2]);
        acc += bs2f(vp[193]) * bs2f(wB[3]);
        acc += bs2f(vp[194]) * w8;
        yout[((size_t)b*CD + c)*HW + (size_t)r*WD + px0 + px] = acc;
    }
}

// ---------------- BN stats from y (float4, 8 slices/channel) ----------------
__global__ void k_bnstat(const float* __restrict__ y, float* __restrict__ bnsum_s,
                         float* __restrict__ bnss_s){
    int blk = blockIdx.x;            // 1024 = 128c x 8 slices
    int c = blk >> 3, slice = blk & 7;
    int tid = threadIdx.x;
    const float4* y4 = (const float4*)y;
    float s = 0.f, ss = 0.f;
    int i0 = slice*2304;
    for (int k = 0; k < 9; ++k){
        int i = i0 + k*256 + tid;
        int b = i / 2304, p4 = i - b*2304;
        float4 v = y4[(size_t)(b*CD + c)*2304 + p4];
        s += v.x + v.y + v.z + v.w;
        ss += v.x*v.x + v.y*v.y + v.z*v.z + v.w*v.w;
    }
    __shared__ float sh[256], sh2[256];
    sh[tid] = s; sh2[tid] = ss;
    __syncthreads();
    for (int st = 128; st > 0; st >>= 1){
        if (tid < st){ sh[tid] += sh[tid+st]; sh2[tid] += sh2[tid+st]; }
        __syncthreads();
    }
    if (tid == 0){
        bnsum_s[c*256 + slice] = sh[0];
        bnss_s [c*256 + slice] = sh2[0];
    }
}

// ================= FALLBACK (R6 embed) =================
template<bool APPLY>
__global__ void k_embed_mfma(const void* __restrict__ x, const int* __restrict__ flags,
                             const bf16* __restrict__ kbuf, const short* __restrict__ canonb,
                             const float* __restrict__ canonf,
                             const float* __restrict__ gmean, const float* __restrict__ gistd,
                             const bf16* __restrict__ vbuf, float* __restrict__ yout,
                             float* __restrict__ gsum_s, float* __restrict__ gsq_s,
                             float* __restrict__ bnsum_s, float* __restrict__ bnss_s){
    __shared__ char buf0[26624];
    __shared__ short w1s[48*72];
    __shared__ short w2s[48*152];
    __shared__ float wsc[WC], wbi[WC];
    __shared__ float blks[256], blkq[256];
    short* qk = (short*)buf0;
    float* yt = (float*)buf0;
    const short* ew1b = canonb + BO_EW1;
    const short* ew2b = canonb + BO_EW2;
    const float* eb2f = canonf + CO_EB2;
    int blk = blockIdx.x;
    int px0 = (blk & 1)*48, r = (blk >> 1) % 96, b = blk / 192;
    int tid = threadIdx.x;
    bool F = flags[0] != 0;
    if (APPLY && tid < WC){
        int g = tid/9;
        float m = gmean[b*NG+g], is = gistd[b*NG+g];
        float ga = canonf[CO_GNG + tid], be = canonf[CO_GNB + tid];
        wsc[tid] = is*ga; wbi[tid] = be - m*is*ga;
    }
    for (int idx = tid; idx < 128*48; idx += 256){
        int c = idx / 48, px = idx - c*48;
        size_t off = ((size_t)b*CD + c)*HW + r*WD + px0 + px;
        float v = F ? ((const float*)x)[off] : b2f(((const bf16*)x)[off]);
        qk[px*264 + c] = f2bs(v);
    }
    for (int idx = tid; idx < 128*48; idx += 256){
        int c = idx / 48, px = idx - c*48;
        qk[px*264 + 128 + c] = ((const short*)kbuf)[((size_t)b*CD + c)*HW + r*WD + px0 + px];
    }
    __syncthreads();
    int wave = tid >> 6, lane = tid & 63, l15 = lane & 15, quad = lane >> 4;
    {
        f4v a1[3];
        #pragma unroll
        for (int n = 0; n < 3; ++n) a1[n] = (f4v){0.f,0.f,0.f,0.f};
        int mb = wave*16;
        for (int k0 = 0; k0 < 256; k0 += 32){
            s8v A = *(const s8v*)(ew1b + (mb + l15)*256 + k0 + quad*8);
            #pragma unroll
            for (int n = 0; n < 3; ++n){
                s8v Bf = *(const s8v*)(qk + (n*16+l15)*264 + k0 + quad*8);
                a1[n] = __builtin_amdgcn_mfma_f32_16x16x32_bf16(A, Bf, a1[n], 0, 0, 0);
            }
        }
        __syncthreads();
        #pragma unroll
        for (int n = 0; n < 3; ++n)
            #pragma unroll
            for (int reg = 0; reg < 4; ++reg){
                int ch = mb + quad*4 + reg;
                int px = n*16 + l15;
                w1s[px*72 + ch] = f2bs(fmaxf(a1[n][reg], 0.f));
            }
    }
    __syncthreads();
    {
        f4v a2[3][3];
        #pragma unroll
        for (int i = 0; i < 3; ++i)
            #pragma unroll
            for (int n = 0; n < 3; ++n) a2[i][n] = (f4v){0.f,0.f,0.f,0.f};
        for (int k0 = 0; k0 < 64; k0 += 32){
            s8v Bf[3];
            #pragma unroll
            for (int n = 0; n < 3; ++n) Bf[n] = *(const s8v*)(w1s + (n*16+l15)*72 + k0 + quad*8);
            #pragma unroll
            for (int i = 0; i < 3; ++i){
                int mt = wave + i*4;
                if (mt >= 9) break;
                s8v A = *(const s8v*)(ew2b + (mt*16 + l15)*64 + k0 + quad*8);
                #pragma unroll
                for (int n = 0; n < 3; ++n)
                    a2[i][n] = __builtin_amdgcn_mfma_f32_16x16x32_bf16(A, Bf[n], a2[i][n], 0, 0, 0);
            }
        }
        #pragma unroll
        for (int i = 0; i < 3; ++i){
            int mt = wave + i*4;
            if (mt >= 9) break;
            #pragma unroll
            for (int n = 0; n < 3; ++n)
                #pragma unroll
                for (int reg = 0; reg < 4; ++reg){
                    int o = mt*16 + quad*4 + reg;
                    int px = n*16 + l15;
                    float val = a2[i][n][reg] + eb2f[o];
                    if (APPLY) val = val*wsc[o] + wbi[o];
                    w2s[px*152 + o] = f2bs(val);
                }
        }
    }
    __syncthreads();
    if (!APPLY){
        if (tid < WC){
            int o = tid; float s = 0.f, ss = 0.f;
            for (int px = 0; px < 48; ++px){ float v = bs2f(w2s[px*152+o]); s += v; ss += v*v; }
            int g = o/9; int slot = blk & 63;
            atomicAdd(&gsum_s[(b*NG+g)*64 + slot], s);
            atomicAdd(&gsq_s [(b*NG+g)*64 + slot], ss);
        }
        return;
    }
    if (tid < 192){
        int px = tid % 48, cq = tid / 48;
        int gcol = px0 + px;
        for (int c = cq*32; c < cq*32 + 32; ++c){
            int g9 = (c >> 3)*9;
            const bf16* vb = vbuf + ((size_t)b*CD + c)*HW;
            float acc = 0.f;
            #pragma unroll
            for (int t = 0; t < 9; ++t){
                int ir = r + t/3 - 1, icc = gcol + t%3 - 1;
                if ((unsigned)ir < 96u && (unsigned)icc < 96u)
                    acc += b2f(vb[ir*WD + icc]) * bs2f(w2s[px*152 + g9 + t]);
            }
            yt[c*52 + px] = acc;
        }
    }
    __syncthreads();
    {
        int c = tid & 127, half = tid >> 7;
        float s = 0.f, ss = 0.f;
        for (int px = half*24; px < half*24 + 24; ++px){
            float v = yt[c*52 + px]; s += v; ss += v*v;
        }
        blks[tid] = s; blkq[tid] = ss;
    }
    __syncthreads();
    if (tid < 128){
        float s = blks[tid] + blks[tid+128];
        float ss = blkq[tid] + blkq[tid+128];
        int slot = blk & 255;
        atomicAdd(&bnsum_s[tid*256 + slot], s);
        atomicAdd(&bnss_s [tid*256 + slot], ss);
    }
    for (int idx = tid; idx < 128*48; idx += 256){
        int c = idx / 48, px = idx - c*48;
        yout[((size_t)b*CD + c)*HW + r*WD + px0 + px] = yt[c*52 + px];
    }
}

// ---------------- GN finalize (fallback path only) ----------------
__global__ void k_gnfin(const float* __restrict__ gsum_s, const float* __restrict__ gsq_s,
                        float* __restrict__ gmean, float* __restrict__ gistd){
    int i = threadIdx.x;
    float s = 0.f, ss = 0.f;
    for (int k = 0; k < 64; ++k){ s += gsum_s[i*64 + k]; ss += gsq_s[i*64 + k]; }
    float inv = 1.f / (9.f*HW);
    float m = s*inv;
    float var = ss*inv - m*m;
    gmean[i] = m;
    gistd[i] = rsqrtf(var + 1e-5f);
}

// ---------------- GAP: inline BN finalize + Sum swish(bn(y)); Sum(k) pre-accumulated ----------------
__global__ void k_gap(const float* __restrict__ ybuf,
                      const float* __restrict__ bnsum_s, const float* __restrict__ bnss_s,
                      const float* __restrict__ canonf,
                      float* __restrict__ gap, float* __restrict__ bscale,
                      float* __restrict__ bshift){
    int blk = blockIdx.x;            // 1024 = 8b x 128c
    int b = blk & 7, c = blk >> 3;
    int bc = b*CD + c;
    int tid = threadIdx.x;
    __shared__ float shm[256], shm2[256];
    __shared__ float sv[2];
    // ---- inline BN finalize for channel c (replaces k_bnfin) ----
    shm[tid]  = bnsum_s[c*256 + tid];
    shm2[tid] = bnss_s [c*256 + tid];
    __syncthreads();
    for (int st = 128; st > 0; st >>= 1){
        if (tid < st){ shm[tid] += shm[tid+st]; shm2[tid] += shm2[tid+st]; }
        __syncthreads();
    }
    if (tid == 0){
        float inv = 1.f / (float)(BD*HW);
        float m = shm[0]*inv;
        float var = shm2[0]*inv - m*m;
        float sc = canonf[CO_BNG + c] * rsqrtf(var + 1e-5f);
        float sh = canonf[CO_BNB + c] - m*sc;
        sv[0] = sc; sv[1] = sh;
        if (b == 0){ bscale[c] = sc; bshift[c] = sh; }
    }
    __syncthreads();
    float sc = sv[0], sh = sv[1];
    const float4* y4 = (const float4*)ybuf + (size_t)bc*2304;
    float gs = 0.f;
    for (int k = 0; k < 9; ++k){
        float4 yv = y4[k*256 + tid];
        #pragma unroll
        for (int j = 0; j < 4; ++j){
            float yn = ((&yv.x)[j])*sc + sh;
            gs += yn / (1.f + __expf(-yn));
        }
    }
    shm[tid] = gs; __syncthreads();
    for (int st = 128; st > 0; st >>= 1){
        if (tid < st) shm[tid] += shm[tid+st];
        __syncthreads();
    }
    if (tid == 0) gap[bc] += shm[0];
}

// ---------------- SE ----------------
__global__ void k_se(const float* __restrict__ gap, const float* __restrict__ canonf,
                     float* __restrict__ p0, float* __restrict__ p1){
    int b = blockIdx.x;
    int tid = threadIdx.x;
    __shared__ float loc[128], h1[64];
    float invhw = 1.f / (float)HW;
    loc[tid]      = gap[b*CD + tid]      * invhw;
    loc[tid + 64] = gap[b*CD + tid + 64] * invhw;
    __syncthreads();
    {
        const float* wr = canonf + CO_SW1 + (size_t)tid*128;
        float acc = canonf[CO_SB1 + tid];
        for (int c = 0; c < 128; ++c) acc += wr[c] * loc[c];
        h1[tid] = fmaxf(acc, 0.f);
    }
    __syncthreads();
    for (int c = tid; c < 128; c += 64){
        float a0 = canonf[CO_SB2 + 2*c], a1 = canonf[CO_SB2 + 2*c+1];
        const float* w0 = canonf + CO_SW2 + (size_t)(2*c)*64;
        const float* w1p = canonf + CO_SW2 + (size_t)(2*c+1)*64;
        for (int j = 0; j < 64; ++j){
            a0 += w0[j] * h1[j];
            a1 += w1p[j] * h1[j];
        }
        float mx = fmaxf(a0, a1);
        float e0 = __expf(a0-mx), e1 = __expf(a1-mx);
        float inv = 1.f / (e0 + e1);
        p0[b*CD+c] = e0*inv;
        p1[b*CD+c] = e1*inv;
    }
}

// ---------------- out: float4 recompute BN+swish, blend, in-place (b-locked XCD swizzle) ----------------
__global__ void k_out(float* __restrict__ ybuf, const bf16* __restrict__ kbuf,
                      const float* __restrict__ scale, const float* __restrict__ shift,
                      const float* __restrict__ p0, const float* __restrict__ p1){
    int blk = blockIdx.x;                              // 9216 = 8b x 1152
    size_t idx = ((size_t)((blk & 7)*1152 + (blk >> 3)))*256 + threadIdx.x;
    int bc = (int)(idx / 2304);
    int c = bc % CD;
    float sc = scale[c], sh = shift[c];
    float q0 = p0[bc], q1 = p1[bc];
    float4 yv = ((const float4*)ybuf)[idx];
    ushort4 kv = ((const ushort4*)kbuf)[idx];
    float4 ov;
    #pragma unroll
    for (int j = 0; j < 4; ++j){
        float yn = ((&yv.x)[j])*sc + sh;
        float ys = yn / (1.f + __expf(-yn));
        (&ov.x)[j] = ys*q0 + bs2f((short)((&kv.x)[j]))*q1;
    }
    ((float4*)ybuf)[idx] = ov;
}

extern "C" void kernel_launch(void* const* d_in, const int* in_sizes, int n_in,
                              void* d_out, int out_size, void* d_ws, size_t ws_size,
                              hipStream_t stream) {
    TensPtrs tp;
    for (int i = 0; i < 14; ++i) tp.p[i] = d_in[i];

    float* f = (float*)d_ws;
    float* bnsum_s = f;            // 32768 (zeroed)
    float* bnss_s  = f + 32768;    // 32768 (zeroed)
    float* gsum_s  = f + 65536;    // 8192  (zeroed)
    float* gsq_s   = f + 73728;    // 8192  (zeroed)
    float* gap     = f + 81920;    // 1024  (zeroed; keyconv accumulates Sum(k) here)
    float* gmean   = f + 82944;
    float* gistd   = f + 83072;
    float* bscale  = f + 83200;
    float* bshift  = f + 83328;
    float* p0      = f + 83456;
    float* p1      = f + 84480;
    int*   flags = (int*)((char*)d_ws + 393216);
    float* canonf = (float*)((char*)d_ws + 425984);
    short* canonb = (short*)((char*)d_ws + 860160);
    bf16*  kbuf  = (bf16*)((char*)d_ws + 1048576);        // 18.87 MB
    bf16*  vbuf  = kbuf + NTOT;                           // 18.87 MB (ends 38,797,312)
    unsigned short* w1b = (unsigned short*)((char*)d_ws + 38797312);  // 9.44 MB (ends 48,234,496)
    float* ybuf  = (float*)d_out;
    short* kwre = (short*)((char*)d_out + KWRE_OFF);      // d_out scratch (pre-y)
    unsigned short* xb16 = (unsigned short*)d_out;        // d_out scratch [0,18.9MB) (f32-x case only)

    bool fast = ws_size >= 48234496ull;

    k_detect<<<14, 256, 0, stream>>>(tp, flags);
    k_canon<<<208, 256, 0, stream>>>(tp, flags, canonf, canonb);
    k_zero<<<324, 256, 0, stream>>>(f, 82944);
    k_xcast<<<1024, 256, 0, stream>>>(d_in[0], flags, xb16);
    k_reorder_kw<<<144, 256, 0, stream>>>(canonb, kwre);
    k_keyconv_mfma<<<768, 256, 0, stream>>>((const short*)xb16, (const short*)d_in[0],
                                            flags, kwre, kbuf, gap);
    if (fast){
        k_embed_stats<<<1536, 256, 0, stream>>>((const short*)xb16, (const short*)d_in[0],
                                                flags, kbuf, canonb, canonf,
                                                w1b, vbuf, gsum_s, gsq_s);
        k_embed_apply<<<1536, 256, 0, stream>>>(w1b, canonb, canonf, gsum_s, gsq_s,
                                                vbuf, ybuf);
        k_bnstat<<<1024, 256, 0, stream>>>(ybuf, bnsum_s, bnss_s);
    } else {
        k_embed_mfma<false><<<1536, 256, 0, stream>>>(d_in[0], flags, kbuf, canonb, canonf,
                                                      gmean, gistd, vbuf, ybuf,
                                                      gsum_s, gsq_s, bnsum_s, bnss_s);
        k_gnfin<<<1, 128, 0, stream>>>(gsum_s, gsq_s, gmean, gistd);
        k_vconv_mfma<<<768, 256, 0, stream>>>(d_in[0], flags, canonb, vbuf);
        k_embed_mfma<true><<<1536, 256, 0, stream>>>(d_in[0], flags, kbuf, canonb, canonf,
                                                     gmean, gistd, vbuf, ybuf,
                                                     gsum_s, gsq_s, bnsum_s, bnss_s);
    }
    k_gap<<<1024, 256, 0, stream>>>(ybuf, bnsum_s, bnss_s, canonf, gap, bscale, bshift);
    k_se<<<BD, 64, 0, stream>>>(gap, canonf, p0, p1);
    k_out<<<(int)(NTOT/4/256), 256, 0, stream>>>(ybuf, kbuf, bscale, bshift, p0, p1);
}